// Round 5
// baseline (3859.896 us; speedup 1.0000x reference)
//
#include <hip/hip_runtime.h>
#include <math.h>

#define DD 1024
#define NP 5120   // padded sample pitch (class offsets padded to 64)
#define PT_TILES 80

typedef _Float16 half8 __attribute__((ext_vector_type(8)));
typedef _Float16 half4 __attribute__((ext_vector_type(4)));
typedef float floatx4 __attribute__((ext_vector_type(4)));
typedef short s16x8 __attribute__((ext_vector_type(8)));

// ---------------- workspace layout (float offsets) ----------------
#define OFF_XTH   ((size_t)0)          // short[1024][5120] bf16 hi
#define OFF_XTL   ((size_t)2621440)    // short[1024][5120] bf16 lo
// UT (packed fp16 V tiles, 4456448 float-slots) overlays [0,...) after syrk
#define OFF_BASE  ((size_t)5242880)    // float[1024][1024]
#define OFF_SIGMA ((size_t)6291456)    // 16*1024*1024 fp32; fp16 Xq overlays after finalize
#define OFF_DINV  ((size_t)23068672)   // 16*16*64*64 fp32
#define OFF_SUMS  ((size_t)24117248)
#define OFF_MU    ((size_t)24133632)
#define OFF_U     ((size_t)24150016)
#define OFF_MU2   ((size_t)24166400)
#define OFF_XQ2   ((size_t)24166416)
#define OFF_XQMU  ((size_t)24170512)
#define OFF_KAPNU ((size_t)24236048)
#define OFF_CF    ((size_t)24236056)
#define OFF_BETA  ((size_t)24236072)
#define OFF_INVS  ((size_t)24236088)
#define OFF_INTS  ((size_t)24236104)   // counts16, offsets16, cls_of_pt80, order[5120]

#define UT_CLS_STRIDE ((size_t)557056) // 136 tiles * 4096 halves

__device__ __forceinline__ void tri_decode(int b, int& ti, int& tj) {
  int t = 0;
  while ((t + 1) * (t + 2) / 2 <= b) t++;
  ti = t;
  tj = b - t * (t + 1) / 2;
}

__device__ __forceinline__ short f2bf(float f) {
  union { float f; unsigned u; } v; v.f = f;
  unsigned r = v.u + 0x7FFF + ((v.u >> 16) & 1);
  return (short)(r >> 16);
}
__device__ __forceinline__ float bf2f(short b) {
  union { unsigned u; float f; } v; v.u = ((unsigned)(unsigned short)b) << 16; return v.f;
}

__device__ __forceinline__ float reduce256(float v, float* scratch) {
  for (int o = 32; o > 0; o >>= 1) v += __shfl_down(v, o, 64);
  int lane = threadIdx.x & 63, w = threadIdx.x >> 6;
  __syncthreads();
  if (lane == 0) scratch[w] = v;
  __syncthreads();
  return scratch[0] + scratch[1] + scratch[2] + scratch[3];
}

// ---------------- stats: hist, scalars, scatter, zero-init (1 block) ----------------
__global__ void k_scalars(const int* y, const float* kappa, const float* nu,
                          float* kapnu, float* cf, float* beta, float* invs,
                          int* counts, int* offsets, int* cls_of_pt, int* order,
                          float* sums, float* uarr, float* dout) {
  __shared__ int h[16];
  __shared__ int cur[16];
  int t = threadIdx.x;
  if (t < 16) h[t] = 0;
  __syncthreads();
  for (int n = t; n < 4096; n += 256) atomicAdd(&h[y[n]], 1);
  __syncthreads();
  if (t == 0) {
    float kap = fabsf(kappa[0]) + 1e-6f;
    float nu_ = fmaxf(nu[0], 1024.0f - 1.0f + 1e-6f);
    kapnu[0] = kap; kapnu[1] = nu_;
    int off = 0, tile = 0;
    for (int c = 0; c < 16; c++) {
      counts[c] = h[c]; offsets[c] = off; cur[c] = off;
      cf[c] = (float)h[c];
      beta[c] = kap + (float)h[c];
      invs[c] = 1.0f / (nu_ + (float)h[c] + 1024.0f + 2.0f);
      int ntile = ((h[c] + 63) & ~63) >> 6;
      for (int q = 0; q < ntile && tile < PT_TILES; q++) cls_of_pt[tile++] = c;
      off += (h[c] + 63) & ~63;
    }
    while (tile < PT_TILES) cls_of_pt[tile++] = -1;
  }
  for (int i = t; i < NP; i += 256) order[i] = -1;
  for (int i = t; i < 16 * 1024; i += 256) { sums[i] = 0.f; uarr[i] = 0.f; }
  for (int i = t; i < 4096 * 16; i += 256) dout[i] = 0.f;
  __syncthreads();
  for (int n = t; n < 4096; n += 256) {
    int c = y[n];
    int p = atomicAdd(&cur[c], 1);
    order[p] = n;
  }
}

// gather + transpose + bf16 hi/lo split + per-class column-sum partials
__global__ void k_gatherT(const float* X, const int* order, const int* cls_of_pt,
                          short* XTh, short* XTl, float* sums) {
  int pt = blockIdx.x, dt = blockIdx.y, t = threadIdx.x;
  __shared__ float T[64 * 66];
  __shared__ float CS[4 * 64];
  __shared__ int src[64];
  if (t < 64) src[t] = order[pt * 64 + t];
  __syncthreads();
  for (int i = 0; i < 16; i++) {
    int lin = i * 256 + t;
    int r = lin >> 6, c = lin & 63;
    int s = src[r];
    T[r * 66 + c] = (s >= 0) ? X[(size_t)s * DD + dt * 64 + c] : 0.f;
  }
  __syncthreads();
  for (int i = 0; i < 16; i++) {
    int lin = i * 256 + t;
    int d = lin >> 6, p = lin & 63;
    float v = T[p * 66 + d];
    short hi = f2bf(v);
    float lov = v - bf2f(hi);
    size_t addr = (size_t)(dt * 64 + d) * NP + pt * 64 + p;
    XTh[addr] = hi;
    XTl[addr] = f2bf(lov);
  }
  int cls = cls_of_pt[pt];
  if (cls < 0) return;
  int g = t >> 6, d = t & 63;
  float s = 0.f;
  for (int p = g * 16; p < g * 16 + 16; p++) s += T[p * 66 + d];
  CS[g * 64 + d] = s;
  __syncthreads();
  if (g == 0)
    atomicAdd(&sums[(size_t)cls * DD + dt * 64 + d],
              CS[d] + CS[64 + d] + CS[128 + d] + CS[192 + d]);
}

// mu + mu2 (one block per class)
__global__ void k_mumu2(const float* sums, const float* m, const float* kapnu,
                        const float* cf, float* mu, float* mu2) {
  __shared__ float scratch[4];
  int c = blockIdx.x, t = threadIdx.x;
  float kap = kapnu[0];
  float denom = 1.0f / (kap + cf[c]);
  float s2 = 0.f;
  for (int j = t; j < DD; j += 256) {
    float v = (kap * m[j] + sums[(size_t)c * DD + j]) * denom;
    mu[(size_t)c * DD + j] = v;
    s2 += v * v;
  }
  float tot = reduce256(s2, scratch);
  if (t == 0) mu2[c] = tot;
}

__device__ __forceinline__ float lval(const float* td, const float* tl, int i, int j) {
  if (i == j) return fabsf(td[i]);
  if (i > j) return tl[(size_t)i * DD + j];
  return 0.f;
}

// base = L*L^T + kap*m*m^T (fp32, lower 64-tiles), L built on the fly
__global__ void k_base(const float* td, const float* tl, const float* m,
                       const float* kapnu, float* base) {
  int ti, tj; tri_decode(blockIdx.x, ti, tj);
  __shared__ float Ta[16][65], Tb[16][65];
  int t = threadIdx.x, tx = t & 15, ty = t >> 4;
  int r0 = ty * 4, c0 = tx * 4;
  float acc[4][4] = {};
  int kmax = (tj + 1) * 64;
  for (int kk = 0; kk < kmax; kk += 16) {
    __syncthreads();
    for (int idx = t; idx < 64 * 16; idx += 256) {
      int r = idx >> 4, p = idx & 15;
      Ta[p][r] = lval(td, tl, ti * 64 + r, kk + p);
      Tb[p][r] = lval(td, tl, tj * 64 + r, kk + p);
    }
    __syncthreads();
#pragma unroll
    for (int p = 0; p < 16; p++) {
      float av[4], bv[4];
#pragma unroll
      for (int a = 0; a < 4; a++) av[a] = Ta[p][r0 + a];
#pragma unroll
      for (int b = 0; b < 4; b++) bv[b] = Tb[p][c0 + b];
#pragma unroll
      for (int a = 0; a < 4; a++)
#pragma unroll
        for (int b = 0; b < 4; b++) acc[a][b] += av[a] * bv[b];
    }
  }
  float kap = kapnu[0];
#pragma unroll
  for (int a = 0; a < 4; a++)
#pragma unroll
    for (int b = 0; b < 4; b++) {
      int gi = ti * 64 + r0 + a, gj = tj * 64 + c0 + b;
      base[(size_t)gi * DD + gj] = acc[a][b] + kap * m[gi] * m[gj];
    }
}

// sigma = (base + X^T X - beta*mu*mu^T) * invs, bf16-split MFMA, lower 128-tiles
__global__ __launch_bounds__(256) void k_syrk_mfma(const short* XTh, const short* XTl,
                                                   const float* base, const float* mu,
                                                   const float* beta, const float* invs,
                                                   const int* counts, const int* offsets,
                                                   float* sigma) {
  int bb = blockIdx.x;
  int cls = bb / 36, tr = bb % 36;
  int ti, tj; tri_decode(tr, ti, tj);
  int cnt = counts[cls], off = offsets[cls];
  float* Sg = sigma + ((size_t)cls << 20);
  const float* muc = mu + (size_t)cls * DD;
  __shared__ short Ah[128 * 40], Al[128 * 40], Bh[128 * 40], Bl[128 * 40];
  int t = threadIdx.x;
  int wave = t >> 6, lane = t & 63;
  int wr = wave >> 1, wc = wave & 1;
  int quad = lane >> 4, l15 = lane & 15;
  int i0 = ti * 128, j0 = tj * 128;
  bool same = (ti == tj);
  floatx4 acc[4][4];
#pragma unroll
  for (int a = 0; a < 4; a++)
#pragma unroll
    for (int b = 0; b < 4; b++) acc[a][b] = (floatx4){0.f, 0.f, 0.f, 0.f};
  for (int nn = 0; nn < cnt; nn += 32) {
    __syncthreads();
#pragma unroll
    for (int r = 0; r < 2; r++) {
      int lin = r * 256 + t;
      int row = lin >> 2, kg = (lin & 3) << 3;
      size_t sA = (size_t)(i0 + row) * NP + off + nn + kg;
      *(s16x8*)&Ah[row * 40 + kg] = *(const s16x8*)&XTh[sA];
      *(s16x8*)&Al[row * 40 + kg] = *(const s16x8*)&XTl[sA];
      if (!same) {
        size_t sB = (size_t)(j0 + row) * NP + off + nn + kg;
        *(s16x8*)&Bh[row * 40 + kg] = *(const s16x8*)&XTh[sB];
        *(s16x8*)&Bl[row * 40 + kg] = *(const s16x8*)&XTl[sB];
      }
    }
    __syncthreads();
    const short* PBh = same ? Ah : Bh;
    const short* PBl = same ? Al : Bl;
    s16x8 ah[4], al[4], bh[4], bl[4];
#pragma unroll
    for (int f = 0; f < 4; f++) {
      ah[f] = *(const s16x8*)&Ah[(wr * 64 + f * 16 + l15) * 40 + quad * 8];
      al[f] = *(const s16x8*)&Al[(wr * 64 + f * 16 + l15) * 40 + quad * 8];
      bh[f] = *(const s16x8*)&PBh[(wc * 64 + f * 16 + l15) * 40 + quad * 8];
      bl[f] = *(const s16x8*)&PBl[(wc * 64 + f * 16 + l15) * 40 + quad * 8];
    }
#pragma unroll
    for (int fi = 0; fi < 4; fi++)
#pragma unroll
      for (int fj = 0; fj < 4; fj++) {
        acc[fi][fj] = __builtin_amdgcn_mfma_f32_16x16x32_bf16(ah[fi], bh[fj], acc[fi][fj], 0, 0, 0);
        acc[fi][fj] = __builtin_amdgcn_mfma_f32_16x16x32_bf16(ah[fi], bl[fj], acc[fi][fj], 0, 0, 0);
        acc[fi][fj] = __builtin_amdgcn_mfma_f32_16x16x32_bf16(al[fi], bh[fj], acc[fi][fj], 0, 0, 0);
      }
  }
  float bet = beta[cls], isc = invs[cls];
#pragma unroll
  for (int fi = 0; fi < 4; fi++)
#pragma unroll
    for (int fj = 0; fj < 4; fj++)
#pragma unroll
      for (int reg = 0; reg < 4; reg++) {
        int gi = i0 + wr * 64 + fi * 16 + quad * 4 + reg;
        int gj = j0 + wc * 64 + fj * 16 + l15;
        float v = acc[fi][fj][reg] + base[(size_t)gi * DD + gj] - bet * muc[gi] * muc[gj];
        Sg[(size_t)gi * DD + gj] = v * isc;
      }
}

// ---------------- factorization (R4-proven bodies) ----------------
__device__ void chol_from_lds(float* Sg, float* Dinv, int cls, int k, int t,
                              float* A, float* W) {
  for (int j = 0; j < 64; j++) {
    if (t == 0) A[j * 66 + j] = sqrtf(A[j * 66 + j]);
    __syncthreads();
    float rpj = 1.0f / A[j * 66 + j];
    for (int r = j + 1 + t; r < 64; r += 256) A[r * 66 + j] *= rpj;
    __syncthreads();
    for (int idx = t; idx < 4096; idx += 256) {
      int r = idx >> 6, c = idx & 63;
      if (r > j && c > j) A[r * 66 + c] -= A[r * 66 + j] * A[c * 66 + j];
    }
    __syncthreads();
  }
  for (int idx = t; idx < 4096; idx += 256) {
    int r = idx >> 6, c = idx & 63;
    W[r * 66 + c] = 0.f;
  }
  __syncthreads();
  if (t < 64) {
    int j = t;
    W[j * 66 + j] = 1.0f / A[j * 66 + j];
    for (int i = j + 1; i < 64; i++) {
      float s = 0.f;
      for (int kk = j; kk < i; kk++) s += A[i * 66 + kk] * W[kk * 66 + j];
      W[i * 66 + j] = -s / A[i * 66 + i];
    }
  }
  __syncthreads();
  for (int idx = t; idx < 4096; idx += 256) {
    int r = idx >> 6, c = idx & 63;
    Sg[(size_t)(k * 64 + r) * DD + k * 64 + c] = (c <= r) ? A[r * 66 + c] : 0.f;
    Dinv[((size_t)(cls * 16 + k)) * 4096 + idx] = W[r * 66 + c];
  }
}

__global__ void k_diag0(float* sigma, float* Dinv) {
  __shared__ float A[64 * 66], W[64 * 66];
  int cls = blockIdx.x, t = threadIdx.x;
  float* Sg = sigma + ((size_t)cls << 20);
  for (int idx = t; idx < 4096; idx += 256) {
    int r = idx >> 6, c = idx & 63;
    A[r * 66 + c] = Sg[(size_t)r * DD + c];
  }
  __syncthreads();
  chol_from_lds(Sg, Dinv, cls, 0, t, A, W);
}

__global__ void k_panel(float* sigma, const float* Dinv, int k) {
  int nb = 15 - k;
  int cls = blockIdx.x / nb, sub = blockIdx.x % nb;
  int it = k + 1 + sub;
  float* Sg = sigma + ((size_t)cls << 20);
  __shared__ float At[64 * 66], Di[64 * 66];
  int t = threadIdx.x, tx = t & 15, ty = t >> 4;
  int r0 = ty * 4, c0 = tx * 4;
  for (int idx = t; idx < 4096; idx += 256) {
    int r = idx >> 6, p = idx & 63;
    At[r * 66 + p] = Sg[(size_t)(it * 64 + r) * DD + k * 64 + p];
    Di[r * 66 + p] = Dinv[((size_t)(cls * 16 + k)) * 4096 + idx];
  }
  __syncthreads();
  float acc[4][4] = {};
#pragma unroll 8
  for (int p = 0; p < 64; p++) {
    float av[4], bv[4];
#pragma unroll
    for (int a = 0; a < 4; a++) av[a] = At[(r0 + a) * 66 + p];
#pragma unroll
    for (int b = 0; b < 4; b++) bv[b] = Di[(c0 + b) * 66 + p];
#pragma unroll
    for (int a = 0; a < 4; a++)
#pragma unroll
      for (int b = 0; b < 4; b++) acc[a][b] += av[a] * bv[b];
  }
#pragma unroll
  for (int a = 0; a < 4; a++)
#pragma unroll
    for (int b = 0; b < 4; b++)
      Sg[(size_t)(it * 64 + r0 + a) * DD + k * 64 + c0 + b] = acc[a][b];
}

__global__ void k_syrkdiag(float* sigma, float* Dinv, int k) {
  __shared__ float La[64 * 66], Lb[64 * 66], Ts[64 * 66];
  int b = blockIdx.x, t = threadIdx.x;
  int tx = t & 15, ty = t >> 4;
  int r0 = ty * 4, c0 = tx * 4;
  int nb = 15 - k;
  int nt = nb * (nb + 1) / 2;
  int cls, it, jt;
  bool special = (b < 16);
  if (special) {
    cls = b; it = k + 1; jt = k + 1;
  } else {
    int jp = b - 16;
    cls = jp / (nt - 1);
    int s = jp % (nt - 1) + 1;
    int a_, b_; tri_decode(s, a_, b_);
    it = k + 1 + a_; jt = k + 1 + b_;
  }
  float* Sg = sigma + ((size_t)cls << 20);
  for (int idx = t; idx < 4096; idx += 256) {
    int r = idx >> 6, p = idx & 63;
    La[r * 66 + p] = Sg[(size_t)(it * 64 + r) * DD + k * 64 + p];
    Lb[r * 66 + p] = Sg[(size_t)(jt * 64 + r) * DD + k * 64 + p];
  }
  __syncthreads();
  float acc[4][4] = {};
#pragma unroll 8
  for (int p = 0; p < 64; p++) {
    float av[4], bv[4];
#pragma unroll
    for (int a = 0; a < 4; a++) av[a] = La[(r0 + a) * 66 + p];
#pragma unroll
    for (int b2 = 0; b2 < 4; b2++) bv[b2] = Lb[(c0 + b2) * 66 + p];
#pragma unroll
    for (int a = 0; a < 4; a++)
#pragma unroll
      for (int b2 = 0; b2 < 4; b2++) acc[a][b2] += av[a] * bv[b2];
  }
  if (!special) {
#pragma unroll
    for (int a = 0; a < 4; a++)
#pragma unroll
      for (int b2 = 0; b2 < 4; b2++) {
        size_t addr = (size_t)(it * 64 + r0 + a) * DD + jt * 64 + c0 + b2;
        Sg[addr] -= acc[a][b2];
      }
    return;
  }
  __syncthreads();
#pragma unroll
  for (int a = 0; a < 4; a++)
#pragma unroll
    for (int b2 = 0; b2 < 4; b2++) {
      size_t addr = (size_t)(it * 64 + r0 + a) * DD + jt * 64 + c0 + b2;
      Ts[(r0 + a) * 66 + c0 + b2] = Sg[addr] - acc[a][b2];
    }
  __syncthreads();
  chol_from_lds(Sg, Dinv, cls, k + 1, t, Ts, La);
}

// single-launch column-parallel V = R^{-1}; block (j, cls) walks i=j+1..15
__global__ void k_vcols(float* sigma, const float* Dinv) {
  int j = blockIdx.x, cls = blockIdx.y;
  float* Sg = sigma + ((size_t)cls << 20);
  const float* Dv = Dinv + (size_t)cls * 16 * 4096;
  __shared__ float Ta[64 * 66], Tb[64 * 66], Ts[64 * 66];
  int t = threadIdx.x, tx = t & 15, ty = t >> 4;
  int r0 = ty * 4, c0 = tx * 4;
  for (int i = j + 1; i <= 15; i++) {
    float acc[4][4] = {};
    for (int k2 = j; k2 < i; k2++) {
      __syncthreads();
      for (int idx = t; idx < 4096; idx += 256) {
        int r = idx >> 6, p = idx & 63;
        Ta[r * 66 + p] = Sg[(size_t)(i * 64 + r) * DD + k2 * 64 + p];
      }
      if (k2 == j) {
        for (int idx = t; idx < 4096; idx += 256) {
          int p = idx >> 6, c = idx & 63;
          Tb[c * 66 + p] = Dv[(size_t)j * 4096 + idx];
        }
      } else {
        for (int idx = t; idx < 4096; idx += 256) {
          int c = idx >> 6, p = idx & 63;
          Tb[c * 66 + p] = Sg[(size_t)(j * 64 + c) * DD + k2 * 64 + p];
        }
      }
      __syncthreads();
#pragma unroll 8
      for (int p = 0; p < 64; p++) {
        float av[4], bv[4];
#pragma unroll
        for (int a = 0; a < 4; a++) av[a] = Ta[(r0 + a) * 66 + p];
#pragma unroll
        for (int b = 0; b < 4; b++) bv[b] = Tb[(c0 + b) * 66 + p];
#pragma unroll
        for (int a = 0; a < 4; a++)
#pragma unroll
          for (int b = 0; b < 4; b++) acc[a][b] += av[a] * bv[b];
      }
    }
    __syncthreads();
#pragma unroll
    for (int a = 0; a < 4; a++)
#pragma unroll
      for (int b = 0; b < 4; b++) Ts[(r0 + a) * 66 + c0 + b] = acc[a][b];
    for (int idx = t; idx < 4096; idx += 256) {
      int r = idx >> 6, p = idx & 63;
      Ta[r * 66 + p] = Dv[(size_t)i * 4096 + idx];
    }
    __syncthreads();
    float acc2[4][4] = {};
#pragma unroll 8
    for (int p = 0; p < 64; p++) {
      float av[4], bv[4];
#pragma unroll
      for (int a = 0; a < 4; a++) av[a] = Ta[(r0 + a) * 66 + p];
#pragma unroll
      for (int b = 0; b < 4; b++) bv[b] = Ts[p * 66 + c0 + b];
#pragma unroll
      for (int a = 0; a < 4; a++)
#pragma unroll
        for (int b = 0; b < 4; b++) acc2[a][b] += av[a] * bv[b];
    }
    __syncthreads();
#pragma unroll
    for (int a = 0; a < 4; a++)
#pragma unroll
      for (int b = 0; b < 4; b++) Ts[(r0 + a) * 66 + c0 + b] = -acc2[a][b];
    __syncthreads();
    for (int idx = t; idx < 4096; idx += 256) {
      int rr = idx & 63, cc = idx >> 6;
      Sg[(size_t)(j * 64 + cc) * DD + i * 64 + rr] = Ts[rr * 66 + cc];
    }
  }
}

// 2176 blocks: packed-fp16 V-tile transpose + fused u-partial (atomicAdd)
__global__ void k_finalize(const float* sigma, const float* Dinv, const float* mu,
                           float* uarr, _Float16* UT) {
  __shared__ float U0[64 * 66];
  __shared__ float CS[4 * 64];
  int jp = blockIdx.x, t = threadIdx.x;
  int cls = jp / 136, tr = jp % 136;
  int nt_, kt_; tri_decode(tr, nt_, kt_);   // nt_ >= kt_
  const float* muc = mu + (size_t)cls * DD;
  _Float16* outp = UT + (size_t)cls * UT_CLS_STRIDE + (size_t)tr * 4096;
  if (kt_ == nt_) {
    const float* Dv = Dinv + ((size_t)(cls * 16 + nt_)) * 4096;
    for (int idx = t; idx < 4096; idx += 256) {
      float w = Dv[idx];
      outp[idx] = (_Float16)w;
      U0[(idx >> 6) * 66 + (idx & 63)] = w;   // U0[r][c] = W[r][c]
    }
    __syncthreads();
    int g = t >> 6, r = t & 63;
    float s = 0.f;
    for (int c = g * 16; c < g * 16 + 16; c++)
      s += U0[r * 66 + c] * muc[nt_ * 64 + c];
    CS[g * 64 + r] = s;
    __syncthreads();
    if (g == 0)
      atomicAdd(&uarr[(size_t)cls * DD + nt_ * 64 + r],
                CS[r] + CS[64 + r] + CS[128 + r] + CS[192 + r]);
  } else {
    const float* Sg = sigma + ((size_t)cls << 20);
    for (int i2 = 0; i2 < 16; i2++) {
      int lin = i2 * 256 + t;
      int kp = lin >> 6, np = lin & 63;
      U0[kp * 66 + np] = Sg[(size_t)(kt_ * 64 + kp) * DD + nt_ * 64 + np];
    }
    __syncthreads();
    for (int i2 = 0; i2 < 16; i2++) {
      int lin = i2 * 256 + t;
      int np = lin >> 6, kp = lin & 63;
      outp[np * 64 + kp] = (_Float16)U0[kp * 66 + np];
    }
    int g = t >> 6, np = t & 63;
    float s = 0.f;
    for (int kp = g * 16; kp < g * 16 + 16; kp++)
      s += U0[kp * 66 + np] * muc[kt_ * 64 + kp];
    CS[g * 64 + np] = s;
    __syncthreads();
    if (g == 0)
      atomicAdd(&uarr[(size_t)cls * DD + nt_ * 64 + np],
                CS[np] + CS[64 + np] + CS[128 + np] + CS[192 + np]);
  }
}

// ---------------- predict side ----------------
__global__ void k_xqdots(const float* Xq, const float* mu, float* xq2, float* xqmu,
                         _Float16* XqH) {
  __shared__ float xrow[DD];
  int m = blockIdx.x, t = threadIdx.x;
  for (int i = t; i < 256; i += 256)
    ((float4*)xrow)[i] = ((const float4*)(Xq + (size_t)m * DD))[i];
  __syncthreads();
  for (int i = t; i < DD; i += 256)
    XqH[(size_t)m * DD + i] = (_Float16)xrow[i];
  int wave = t >> 6, lane = t & 63;
  for (int cc = 0; cc < 4; cc++) {
    int c = wave * 4 + cc;
    const float* muc = mu + (size_t)c * DD;
    float s = 0.f;
    for (int j = lane; j < DD; j += 64) s += xrow[j] * muc[j];
    for (int o = 32; o > 0; o >>= 1) s += __shfl_down(s, o, 64);
    if (lane == 0) xqmu[(size_t)m * 16 + c] = s;
  }
  if (wave == 0) {
    float s = 0.f;
    for (int j = lane; j < DD; j += 64) s += xrow[j] * xrow[j];
    for (int o = 32; o > 0; o >>= 1) s += __shfl_down(s, o, 64);
    if (lane == 0) xq2[m] = s;
  }
}

// G = Xq * V^T per class from packed fp16 tiles, fused ||G-u||^2 epilogue
__global__ __launch_bounds__(256) void k_gemmG_mfma(const _Float16* XqH, const _Float16* UT,
                                                    const float* u, float* dout) {
  int mt = blockIdx.x, ct = blockIdx.y, cls = blockIdx.z;
  const _Float16* Uc = UT + (size_t)cls * UT_CLS_STRIDE;
  __shared__ _Float16 As[128 * 40];
  __shared__ _Float16 Bs[128 * 40];
  int t = threadIdx.x;
  int wave = t >> 6, lane = t & 63;
  int wr = wave >> 1, wc = wave & 1;
  int quad = lane >> 4, l15 = lane & 15;
  int m0 = mt * 128, n0 = ct * 128, NT0 = ct * 2;
  floatx4 acc[4][4];
#pragma unroll
  for (int a = 0; a < 4; a++)
#pragma unroll
    for (int b = 0; b < 4; b++) acc[a][b] = (floatx4){0.f, 0.f, 0.f, 0.f};
  int kmax = (ct + 1) * 128;
  for (int kk = 0; kk < kmax; kk += 32) {
    __syncthreads();
#pragma unroll
    for (int i = 0; i < 2; i++) {
      int lin = i * 256 + t;
      int r = lin >> 2, kg = (lin & 3) * 8;
      *(half8*)&As[r * 40 + kg] = *(const half8*)&XqH[(size_t)(m0 + r) * DD + kk + kg];
    }
    int kt = kk >> 6, k0 = kk & 63;
#pragma unroll
    for (int i = 0; i < 2; i++) {
      int lin = i * 256 + t;
      int nl = lin >> 2, kg = (lin & 3) * 8;
      int s = nl >> 6, np = nl & 63;
      int nt = NT0 + s;
      half8 v = {};
      if (kt <= nt)
        v = *(const half8*)&Uc[(size_t)(nt * (nt + 1) / 2 + kt) * 4096 + np * 64 + k0 + kg];
      *(half8*)&Bs[nl * 40 + kg] = v;
    }
    __syncthreads();
    half8 af[4], bf[4];
#pragma unroll
    for (int f = 0; f < 4; f++) {
      af[f] = *(const half8*)&As[(wr * 64 + f * 16 + l15) * 40 + quad * 8];
      bf[f] = *(const half8*)&Bs[(wc * 64 + f * 16 + l15) * 40 + quad * 8];
    }
#pragma unroll
    for (int fi = 0; fi < 4; fi++)
#pragma unroll
      for (int fj = 0; fj < 4; fj++)
        acc[fi][fj] = __builtin_amdgcn_mfma_f32_16x16x32_f16(af[fi], bf[fj], acc[fi][fj], 0, 0, 0);
  }
  float uv[4];
#pragma unroll
  for (int fj = 0; fj < 4; fj++)
    uv[fj] = u[(size_t)cls * DD + n0 + wc * 64 + fj * 16 + l15];
#pragma unroll
  for (int fi = 0; fi < 4; fi++) {
#pragma unroll
    for (int r = 0; r < 4; r++) {
      float p = 0.f;
#pragma unroll
      for (int fj = 0; fj < 4; fj++) {
        float e = acc[fi][fj][r] - uv[fj];
        p += e * e;
      }
      p += __shfl_xor(p, 1, 64);
      p += __shfl_xor(p, 2, 64);
      p += __shfl_xor(p, 4, 64);
      p += __shfl_xor(p, 8, 64);
      if (l15 == 0) {
        int m = m0 + wr * 64 + fi * 16 + quad * 4 + r;
        atomicAdd(&dout[(size_t)m * 16 + cls], p);
      }
    }
  }
}

__global__ void k_logits(const float* xq2, const float* xqmu, const float* mu2,
                         float* dout) {
  size_t idx = (size_t)blockIdx.x * 256 + threadIdx.x;
  int m = (int)(idx >> 4), c = (int)(idx & 15);
  float q1 = dout[idx];
  float q2 = xq2[m] - 2.0f * xqmu[idx] + mu2[c];
  dout[idx] = -(0.9f * q1 + 0.1f * q2);
}

extern "C" void kernel_launch(void* const* d_in, const int* in_sizes, int n_in,
                              void* d_out, int out_size, void* d_ws, size_t ws_size,
                              hipStream_t stream) {
  (void)in_sizes; (void)n_in; (void)out_size; (void)ws_size;
  const float* X  = (const float*)d_in[0];
  const int*   y  = (const int*)d_in[1];
  const float* Xq = (const float*)d_in[2];
  const float* m  = (const float*)d_in[3];
  const float* kappa = (const float*)d_in[4];
  const float* nu = (const float*)d_in[5];
  const float* td = (const float*)d_in[6];
  const float* tl = (const float*)d_in[7];
  float* out = (float*)d_out;
  float* ws = (float*)d_ws;

  short* XTh   = (short*)(ws + OFF_XTH);
  short* XTl   = (short*)(ws + OFF_XTL);
  _Float16* UT = (_Float16*)ws;              // overlays XT planes (dead after syrk)
  float* baseb = ws + OFF_BASE;
  float* sigma = ws + OFF_SIGMA;
  _Float16* XqH = (_Float16*)sigma;          // overlays sigma (dead after finalize)
  float* Dinv  = ws + OFF_DINV;
  float* sums  = ws + OFF_SUMS;
  float* mu    = ws + OFF_MU;
  float* uarr  = ws + OFF_U;
  float* mu2   = ws + OFF_MU2;
  float* xq2   = ws + OFF_XQ2;
  float* xqmu  = ws + OFF_XQMU;
  float* kapnu = ws + OFF_KAPNU;
  float* cf    = ws + OFF_CF;
  float* beta  = ws + OFF_BETA;
  float* invs  = ws + OFF_INVS;
  int* ints      = (int*)(ws + OFF_INTS);
  int* counts    = ints;
  int* offsets   = ints + 16;
  int* cls_of_pt = ints + 32;
  int* order     = ints + 32 + PT_TILES;

  k_scalars<<<1, 256, 0, stream>>>(y, kappa, nu, kapnu, cf, beta, invs,
                                   counts, offsets, cls_of_pt, order,
                                   sums, uarr, out);
  k_gatherT<<<dim3(PT_TILES, 16), 256, 0, stream>>>(X, order, cls_of_pt, XTh, XTl, sums);
  k_mumu2<<<16, 256, 0, stream>>>(sums, m, kapnu, cf, mu, mu2);
  k_base<<<136, 256, 0, stream>>>(td, tl, m, kapnu, baseb);
  k_syrk_mfma<<<16 * 36, 256, 0, stream>>>(XTh, XTl, baseb, mu, beta, invs,
                                           counts, offsets, sigma);
  k_diag0<<<16, 256, 0, stream>>>(sigma, Dinv);
  for (int k = 0; k < 15; k++) {
    int nb = 15 - k;
    k_panel<<<16 * nb, 256, 0, stream>>>(sigma, Dinv, k);
    int nt = nb * (nb + 1) / 2;
    k_syrkdiag<<<16 * nt, 256, 0, stream>>>(sigma, Dinv, k);
  }
  k_vcols<<<dim3(15, 16), 256, 0, stream>>>(sigma, Dinv);
  k_finalize<<<16 * 136, 256, 0, stream>>>(sigma, Dinv, mu, uarr, UT);
  k_xqdots<<<4096, 256, 0, stream>>>(Xq, mu, xq2, xqmu, XqH);
  k_gemmG_mfma<<<dim3(32, 8, 16), 256, 0, stream>>>(XqH, UT, uarr, out);
  k_logits<<<256, 256, 0, stream>>>(xq2, xqmu, mu2, out);
}

// Round 6
// 3156.734 us; speedup vs baseline: 1.2227x; 1.2227x over previous
//
#include <hip/hip_runtime.h>
#include <math.h>

#define DD 1024
#define NP 5120   // padded sample pitch (class offsets padded to 64)
#define PT_TILES 80

typedef _Float16 half8 __attribute__((ext_vector_type(8)));
typedef _Float16 half4 __attribute__((ext_vector_type(4)));
typedef float floatx4 __attribute__((ext_vector_type(4)));
typedef short s16x8 __attribute__((ext_vector_type(8)));

// ---------------- workspace layout (float offsets) ----------------
#define OFF_XTH   ((size_t)0)
#define OFF_XTL   ((size_t)2621440)
#define OFF_BASE  ((size_t)5242880)
#define OFF_SIGMA ((size_t)6291456)    // 16*1024*1024 fp32 (lower: Schur/T-scratch, upper: R panels then V)
#define OFF_DINV  ((size_t)23068672)
#define OFF_SUMS  ((size_t)24117248)
#define OFF_MU    ((size_t)24133632)
#define OFF_U     ((size_t)24150016)
#define OFF_MU2   ((size_t)24166400)
#define OFF_XQ2   ((size_t)24166416)
#define OFF_XQMU  ((size_t)24170512)
#define OFF_KAPNU ((size_t)24236048)
#define OFF_CF    ((size_t)24236056)
#define OFF_BETA  ((size_t)24236072)
#define OFF_INVS  ((size_t)24236088)
#define OFF_INTS  ((size_t)24236104)

#define UT_CLS_STRIDE ((size_t)557056) // 136 tiles * 4096 halves

__device__ __forceinline__ void tri_decode(int b, int& ti, int& tj) {
  int t = 0;
  while ((t + 1) * (t + 2) / 2 <= b) t++;
  ti = t;
  tj = b - t * (t + 1) / 2;
}

__device__ __forceinline__ short f2bf(float f) {
  union { float f; unsigned u; } v; v.f = f;
  unsigned r = v.u + 0x7FFF + ((v.u >> 16) & 1);
  return (short)(r >> 16);
}
__device__ __forceinline__ float bf2f(short b) {
  union { unsigned u; float f; } v; v.u = ((unsigned)(unsigned short)b) << 16; return v.f;
}

__device__ __forceinline__ float reduce256(float v, float* scratch) {
  for (int o = 32; o > 0; o >>= 1) v += __shfl_down(v, o, 64);
  int lane = threadIdx.x & 63, w = threadIdx.x >> 6;
  __syncthreads();
  if (lane == 0) scratch[w] = v;
  __syncthreads();
  return scratch[0] + scratch[1] + scratch[2] + scratch[3];
}

// ---------------- stats ----------------
__global__ void k_scalars(const int* y, const float* kappa, const float* nu,
                          float* kapnu, float* cf, float* beta, float* invs,
                          int* counts, int* offsets, int* cls_of_pt, int* order,
                          float* sums, float* uarr, float* dout) {
  __shared__ int h[16];
  __shared__ int cur[16];
  int t = threadIdx.x;
  if (t < 16) h[t] = 0;
  __syncthreads();
  for (int n = t; n < 4096; n += 256) atomicAdd(&h[y[n]], 1);
  __syncthreads();
  if (t == 0) {
    float kap = fabsf(kappa[0]) + 1e-6f;
    float nu_ = fmaxf(nu[0], 1024.0f - 1.0f + 1e-6f);
    kapnu[0] = kap; kapnu[1] = nu_;
    int off = 0, tile = 0;
    for (int c = 0; c < 16; c++) {
      counts[c] = h[c]; offsets[c] = off; cur[c] = off;
      cf[c] = (float)h[c];
      beta[c] = kap + (float)h[c];
      invs[c] = 1.0f / (nu_ + (float)h[c] + 1024.0f + 2.0f);
      int ntile = ((h[c] + 63) & ~63) >> 6;
      for (int q = 0; q < ntile && tile < PT_TILES; q++) cls_of_pt[tile++] = c;
      off += (h[c] + 63) & ~63;
    }
    while (tile < PT_TILES) cls_of_pt[tile++] = -1;
  }
  for (int i = t; i < NP; i += 256) order[i] = -1;
  for (int i = t; i < 16 * 1024; i += 256) { sums[i] = 0.f; uarr[i] = 0.f; }
  for (int i = t; i < 4096 * 16; i += 256) dout[i] = 0.f;
  __syncthreads();
  for (int n = t; n < 4096; n += 256) {
    int c = y[n];
    int p = atomicAdd(&cur[c], 1);
    order[p] = n;
  }
}

__global__ void k_gatherT(const float* X, const int* order, const int* cls_of_pt,
                          short* XTh, short* XTl, float* sums) {
  int pt = blockIdx.x, dt = blockIdx.y, t = threadIdx.x;
  __shared__ float T[64 * 66];
  __shared__ float CS[4 * 64];
  __shared__ int src[64];
  if (t < 64) src[t] = order[pt * 64 + t];
  __syncthreads();
  for (int i = 0; i < 16; i++) {
    int lin = i * 256 + t;
    int r = lin >> 6, c = lin & 63;
    int s = src[r];
    T[r * 66 + c] = (s >= 0) ? X[(size_t)s * DD + dt * 64 + c] : 0.f;
  }
  __syncthreads();
  for (int i = 0; i < 16; i++) {
    int lin = i * 256 + t;
    int d = lin >> 6, p = lin & 63;
    float v = T[p * 66 + d];
    short hi = f2bf(v);
    float lov = v - bf2f(hi);
    size_t addr = (size_t)(dt * 64 + d) * NP + pt * 64 + p;
    XTh[addr] = hi;
    XTl[addr] = f2bf(lov);
  }
  int cls = cls_of_pt[pt];
  if (cls < 0) return;
  int g = t >> 6, d = t & 63;
  float s = 0.f;
  for (int p = g * 16; p < g * 16 + 16; p++) s += T[p * 66 + d];
  CS[g * 64 + d] = s;
  __syncthreads();
  if (g == 0)
    atomicAdd(&sums[(size_t)cls * DD + dt * 64 + d],
              CS[d] + CS[64 + d] + CS[128 + d] + CS[192 + d]);
}

__global__ void k_mumu2(const float* sums, const float* m, const float* kapnu,
                        const float* cf, float* mu, float* mu2) {
  __shared__ float scratch[4];
  int c = blockIdx.x, t = threadIdx.x;
  float kap = kapnu[0];
  float denom = 1.0f / (kap + cf[c]);
  float s2 = 0.f;
  for (int j = t; j < DD; j += 256) {
    float v = (kap * m[j] + sums[(size_t)c * DD + j]) * denom;
    mu[(size_t)c * DD + j] = v;
    s2 += v * v;
  }
  float tot = reduce256(s2, scratch);
  if (t == 0) mu2[c] = tot;
}

__device__ __forceinline__ float lval(const float* td, const float* tl, int i, int j) {
  if (i == j) return fabsf(td[i]);
  if (i > j) return tl[(size_t)i * DD + j];
  return 0.f;
}

__global__ void k_base(const float* td, const float* tl, const float* m,
                       const float* kapnu, float* base) {
  int ti, tj; tri_decode(blockIdx.x, ti, tj);
  __shared__ float Ta[16][65], Tb[16][65];
  int t = threadIdx.x, tx = t & 15, ty = t >> 4;
  int r0 = ty * 4, c0 = tx * 4;
  float acc[4][4] = {};
  int kmax = (tj + 1) * 64;
  for (int kk = 0; kk < kmax; kk += 16) {
    __syncthreads();
    for (int idx = t; idx < 64 * 16; idx += 256) {
      int r = idx >> 4, p = idx & 15;
      Ta[p][r] = lval(td, tl, ti * 64 + r, kk + p);
      Tb[p][r] = lval(td, tl, tj * 64 + r, kk + p);
    }
    __syncthreads();
#pragma unroll
    for (int p = 0; p < 16; p++) {
      float av[4], bv[4];
#pragma unroll
      for (int a = 0; a < 4; a++) av[a] = Ta[p][r0 + a];
#pragma unroll
      for (int b = 0; b < 4; b++) bv[b] = Tb[p][c0 + b];
#pragma unroll
      for (int a = 0; a < 4; a++)
#pragma unroll
        for (int b = 0; b < 4; b++) acc[a][b] += av[a] * bv[b];
    }
  }
  float kap = kapnu[0];
#pragma unroll
  for (int a = 0; a < 4; a++)
#pragma unroll
    for (int b = 0; b < 4; b++) {
      int gi = ti * 64 + r0 + a, gj = tj * 64 + c0 + b;
      base[(size_t)gi * DD + gj] = acc[a][b] + kap * m[gi] * m[gj];
    }
}

__global__ __launch_bounds__(256) void k_syrk_mfma(const short* XTh, const short* XTl,
                                                   const float* base, const float* mu,
                                                   const float* beta, const float* invs,
                                                   const int* counts, const int* offsets,
                                                   float* sigma) {
  int bb = blockIdx.x;
  int cls = bb / 36, tr = bb % 36;
  int ti, tj; tri_decode(tr, ti, tj);
  int cnt = counts[cls], off = offsets[cls];
  float* Sg = sigma + ((size_t)cls << 20);
  const float* muc = mu + (size_t)cls * DD;
  __shared__ short Ah[128 * 40], Al[128 * 40], Bh[128 * 40], Bl[128 * 40];
  int t = threadIdx.x;
  int wave = t >> 6, lane = t & 63;
  int wr = wave >> 1, wc = wave & 1;
  int quad = lane >> 4, l15 = lane & 15;
  int i0 = ti * 128, j0 = tj * 128;
  bool same = (ti == tj);
  floatx4 acc[4][4];
#pragma unroll
  for (int a = 0; a < 4; a++)
#pragma unroll
    for (int b = 0; b < 4; b++) acc[a][b] = (floatx4){0.f, 0.f, 0.f, 0.f};
  for (int nn = 0; nn < cnt; nn += 32) {
    __syncthreads();
#pragma unroll
    for (int r = 0; r < 2; r++) {
      int lin = r * 256 + t;
      int row = lin >> 2, kg = (lin & 3) << 3;
      size_t sA = (size_t)(i0 + row) * NP + off + nn + kg;
      *(s16x8*)&Ah[row * 40 + kg] = *(const s16x8*)&XTh[sA];
      *(s16x8*)&Al[row * 40 + kg] = *(const s16x8*)&XTl[sA];
      if (!same) {
        size_t sB = (size_t)(j0 + row) * NP + off + nn + kg;
        *(s16x8*)&Bh[row * 40 + kg] = *(const s16x8*)&XTh[sB];
        *(s16x8*)&Bl[row * 40 + kg] = *(const s16x8*)&XTl[sB];
      }
    }
    __syncthreads();
    const short* PBh = same ? Ah : Bh;
    const short* PBl = same ? Al : Bl;
    s16x8 ah[4], al[4], bh[4], bl[4];
#pragma unroll
    for (int f = 0; f < 4; f++) {
      ah[f] = *(const s16x8*)&Ah[(wr * 64 + f * 16 + l15) * 40 + quad * 8];
      al[f] = *(const s16x8*)&Al[(wr * 64 + f * 16 + l15) * 40 + quad * 8];
      bh[f] = *(const s16x8*)&PBh[(wc * 64 + f * 16 + l15) * 40 + quad * 8];
      bl[f] = *(const s16x8*)&PBl[(wc * 64 + f * 16 + l15) * 40 + quad * 8];
    }
#pragma unroll
    for (int fi = 0; fi < 4; fi++)
#pragma unroll
      for (int fj = 0; fj < 4; fj++) {
        acc[fi][fj] = __builtin_amdgcn_mfma_f32_16x16x32_bf16(ah[fi], bh[fj], acc[fi][fj], 0, 0, 0);
        acc[fi][fj] = __builtin_amdgcn_mfma_f32_16x16x32_bf16(ah[fi], bl[fj], acc[fi][fj], 0, 0, 0);
        acc[fi][fj] = __builtin_amdgcn_mfma_f32_16x16x32_bf16(al[fi], bh[fj], acc[fi][fj], 0, 0, 0);
      }
  }
  float bet = beta[cls], isc = invs[cls];
#pragma unroll
  for (int fi = 0; fi < 4; fi++)
#pragma unroll
    for (int fj = 0; fj < 4; fj++)
#pragma unroll
      for (int reg = 0; reg < 4; reg++) {
        int gi = i0 + wr * 64 + fi * 16 + quad * 4 + reg;
        int gj = j0 + wc * 64 + fj * 16 + l15;
        float v = acc[fi][fj][reg] + base[(size_t)gi * DD + gj] - bet * muc[gi] * muc[gj];
        Sg[(size_t)gi * DD + gj] = v * isc;
      }
}

// ---------------- factorization ----------------
__device__ void chol_from_lds(float* Sg, float* Dinv, int cls, int k, int t,
                              float* A, float* W) {
  for (int j = 0; j < 64; j++) {
    if (t == 0) A[j * 66 + j] = sqrtf(A[j * 66 + j]);
    __syncthreads();
    float rpj = 1.0f / A[j * 66 + j];
    for (int r = j + 1 + t; r < 64; r += 256) A[r * 66 + j] *= rpj;
    __syncthreads();
    for (int idx = t; idx < 4096; idx += 256) {
      int r = idx >> 6, c = idx & 63;
      if (r > j && c > j) A[r * 66 + c] -= A[r * 66 + j] * A[c * 66 + j];
    }
    __syncthreads();
  }
  for (int idx = t; idx < 4096; idx += 256) {
    int r = idx >> 6, c = idx & 63;
    W[r * 66 + c] = 0.f;
  }
  __syncthreads();
  if (t < 64) {
    int j = t;
    W[j * 66 + j] = 1.0f / A[j * 66 + j];
    for (int i = j + 1; i < 64; i++) {
      float s = 0.f;
      for (int kk = j; kk < i; kk++) s += A[i * 66 + kk] * W[kk * 66 + j];
      W[i * 66 + j] = -s / A[i * 66 + i];
    }
  }
  __syncthreads();
  for (int idx = t; idx < 4096; idx += 256) {
    int r = idx >> 6, c = idx & 63;
    Sg[(size_t)(k * 64 + r) * DD + k * 64 + c] = (c <= r) ? A[r * 66 + c] : 0.f;
    Dinv[((size_t)(cls * 16 + k)) * 4096 + idx] = W[r * 66 + c];
  }
}

__global__ void k_diag0(float* sigma, float* Dinv) {
  __shared__ float A[64 * 66], W[64 * 66];
  int cls = blockIdx.x, t = threadIdx.x;
  float* Sg = sigma + ((size_t)cls << 20);
  for (int idx = t; idx < 4096; idx += 256) {
    int r = idx >> 6, c = idx & 63;
    A[r * 66 + c] = Sg[(size_t)r * DD + c];
  }
  __syncthreads();
  chol_from_lds(Sg, Dinv, cls, 0, t, A, W);
}

// merged step k: every block recomputes its panels P_i = A(i,k)*W_k^T in LDS,
// blocks with b_==0 persist P(it,k) to the UPPER mirror (k, it); trailing
// S(it,jt) -= P_i P_j^T into lower; special block also factors diag k+1 in LDS.
__global__ void k_cholstep(float* sigma, float* Dinv, int k) {
  __shared__ float B0[64 * 66], B1[64 * 66], B2[64 * 66];
  int b = blockIdx.x, t = threadIdx.x;
  int tx = t & 15, ty = t >> 4;
  int r0 = ty * 4, c0 = tx * 4;
  int nb = 15 - k;
  int nt = nb * (nb + 1) / 2;
  int cls, a_, b_;
  bool special = (b < 16);
  if (special) { cls = b; a_ = 0; b_ = 0; }
  else {
    int jp = b - 16;
    cls = jp / (nt - 1);
    int s = jp % (nt - 1) + 1;
    tri_decode(s, a_, b_);
  }
  int it = k + 1 + a_, jt = k + 1 + b_;
  bool same = (it == jt);
  float* Sg = sigma + ((size_t)cls << 20);
  for (int idx = t; idx < 4096; idx += 256) {
    int r = idx >> 6, p = idx & 63;
    B0[r * 66 + p] = Dinv[((size_t)(cls * 16 + k)) * 4096 + idx];
    B1[r * 66 + p] = Sg[(size_t)(it * 64 + r) * DD + k * 64 + p];
    if (!same) B2[r * 66 + p] = Sg[(size_t)(jt * 64 + r) * DD + k * 64 + p];
  }
  __syncthreads();
  float a1[4][4] = {}, a2[4][4] = {};
#pragma unroll 8
  for (int p = 0; p < 64; p++) {
    float av[4], bv[4];
#pragma unroll
    for (int a = 0; a < 4; a++) av[a] = B1[(r0 + a) * 66 + p];
#pragma unroll
    for (int bq = 0; bq < 4; bq++) bv[bq] = B0[(c0 + bq) * 66 + p];
#pragma unroll
    for (int a = 0; a < 4; a++)
#pragma unroll
      for (int bq = 0; bq < 4; bq++) a1[a][bq] += av[a] * bv[bq];
  }
  if (!same) {
#pragma unroll 8
    for (int p = 0; p < 64; p++) {
      float av[4], bv[4];
#pragma unroll
      for (int a = 0; a < 4; a++) av[a] = B2[(r0 + a) * 66 + p];
#pragma unroll
      for (int bq = 0; bq < 4; bq++) bv[bq] = B0[(c0 + bq) * 66 + p];
#pragma unroll
      for (int a = 0; a < 4; a++)
#pragma unroll
        for (int bq = 0; bq < 4; bq++) a2[a][bq] += av[a] * bv[bq];
    }
  }
  __syncthreads();
#pragma unroll
  for (int a = 0; a < 4; a++)
#pragma unroll
    for (int bq = 0; bq < 4; bq++) {
      B1[(r0 + a) * 66 + c0 + bq] = a1[a][bq];
      if (!same) B2[(r0 + a) * 66 + c0 + bq] = a2[a][bq];
    }
  if (b_ == 0) {
#pragma unroll
    for (int a = 0; a < 4; a++) {
      float4 v = make_float4(a1[a][0], a1[a][1], a1[a][2], a1[a][3]);
      *(float4*)&Sg[(size_t)(k * 64 + r0 + a) * DD + it * 64 + c0] = v;
    }
  }
  __syncthreads();
  float* PB = same ? B1 : B2;
  float a3[4][4] = {};
#pragma unroll 8
  for (int p = 0; p < 64; p++) {
    float av[4], bv[4];
#pragma unroll
    for (int a = 0; a < 4; a++) av[a] = B1[(r0 + a) * 66 + p];
#pragma unroll
    for (int bq = 0; bq < 4; bq++) bv[bq] = PB[(c0 + bq) * 66 + p];
#pragma unroll
    for (int a = 0; a < 4; a++)
#pragma unroll
      for (int bq = 0; bq < 4; bq++) a3[a][bq] += av[a] * bv[bq];
  }
  if (!special) {
#pragma unroll
    for (int a = 0; a < 4; a++)
#pragma unroll
      for (int bq = 0; bq < 4; bq++) {
        size_t addr = (size_t)(it * 64 + r0 + a) * DD + jt * 64 + c0 + bq;
        Sg[addr] -= a3[a][bq];
      }
    return;
  }
  __syncthreads();
#pragma unroll
  for (int a = 0; a < 4; a++)
#pragma unroll
    for (int bq = 0; bq < 4; bq++) {
      size_t addr = (size_t)(it * 64 + r0 + a) * DD + jt * 64 + c0 + bq;
      B0[(r0 + a) * 66 + c0 + bq] = Sg[addr] - a3[a][bq];
    }
  __syncthreads();
  chol_from_lds(Sg, Dinv, cls, k + 1, t, B0, B2);
}

// level-1 V combine (width 64->128), fully in-LDS: V21 = -W1 * R * W0
__global__ void k_vl1(float* sigma, const float* Dinv) {
  __shared__ float Rl[64 * 66], W0s[64 * 66], W1s[64 * 66], Ts[64 * 66];
  int b = blockIdx.x, t = threadIdx.x;
  int cls = b >> 3, i = b & 7;
  int t0 = 2 * i, t1 = 2 * i + 1;
  float* Sg = sigma + ((size_t)cls << 20);
  int tx = t & 15, ty = t >> 4;
  int r0 = ty * 4, c0 = tx * 4;
  for (int idx = t; idx < 4096; idx += 256) {
    int r = idx >> 6, p = idx & 63;
    Rl[r * 66 + p] = Sg[(size_t)(t0 * 64 + r) * DD + t1 * 64 + p];     // R(t1,t0)[r][p]
    W0s[r * 66 + p] = Dinv[((size_t)(cls * 16 + t0)) * 4096 + idx];     // W0[p][c] layout [r=p][c]
    W1s[r * 66 + p] = Dinv[((size_t)(cls * 16 + t1)) * 4096 + idx];     // W1[r][p]
  }
  __syncthreads();
  float aT[4][4] = {};
#pragma unroll 8
  for (int p = 0; p < 64; p++) {
    float av[4], bv[4];
#pragma unroll
    for (int a = 0; a < 4; a++) av[a] = Rl[(r0 + a) * 66 + p];
#pragma unroll
    for (int bq = 0; bq < 4; bq++) bv[bq] = W0s[p * 66 + c0 + bq];
#pragma unroll
    for (int a = 0; a < 4; a++)
#pragma unroll
      for (int bq = 0; bq < 4; bq++) aT[a][bq] += av[a] * bv[bq];
  }
  __syncthreads();
#pragma unroll
  for (int a = 0; a < 4; a++)
#pragma unroll
    for (int bq = 0; bq < 4; bq++) Ts[(r0 + a) * 66 + c0 + bq] = aT[a][bq];
  __syncthreads();
  float aV[4][4] = {};
#pragma unroll 8
  for (int p = 0; p < 64; p++) {
    float av[4], bv[4];
#pragma unroll
    for (int a = 0; a < 4; a++) av[a] = W1s[(r0 + a) * 66 + p];
#pragma unroll
    for (int bq = 0; bq < 4; bq++) bv[bq] = Ts[p * 66 + c0 + bq];
#pragma unroll
    for (int a = 0; a < 4; a++)
#pragma unroll
      for (int bq = 0; bq < 4; bq++) aV[a][bq] += av[a] * bv[bq];
  }
#pragma unroll
  for (int a = 0; a < 4; a++)
#pragma unroll
    for (int bq = 0; bq < 4; bq++)
      Sg[(size_t)(t0 * 64 + r0 + a) * DD + t1 * 64 + c0 + bq] = -aV[a][bq];
}

// level-L launch A: T(a,b) = sum_m R21(a,m) * V11(m,b); T -> lower scratch
__global__ void k_vlA(float* sigma, const float* Dinv, int w) {
  __shared__ float Xs[64 * 66], Ys[64 * 66];
  int aa = blockIdx.x / w, bb = blockIdx.x % w;
  int base = blockIdx.y * 2 * w, cls = blockIdx.z;
  float* Sg = sigma + ((size_t)cls << 20);
  int t = threadIdx.x, tx = t & 15, ty = t >> 4;
  int r0 = ty * 4, c0 = tx * 4;
  float acc[4][4] = {};
  for (int m = bb; m < w; m++) {
    __syncthreads();
    for (int idx = t; idx < 4096; idx += 256) {
      int r = idx >> 6, p = idx & 63;
      Xs[r * 66 + p] = Sg[(size_t)((base + m) * 64 + r) * DD + (base + w + aa) * 64 + p];
    }
    if (m == bb) {
      const float* Dv = Dinv + ((size_t)(cls * 16 + base + bb)) * 4096;
      for (int idx = t; idx < 4096; idx += 256)
        Ys[(idx >> 6) * 66 + (idx & 63)] = Dv[idx];
    } else {
      for (int idx = t; idx < 4096; idx += 256) {
        int p = idx >> 6, c = idx & 63;
        Ys[p * 66 + c] = Sg[(size_t)((base + bb) * 64 + p) * DD + (base + m) * 64 + c];
      }
    }
    __syncthreads();
#pragma unroll 8
    for (int p = 0; p < 64; p++) {
      float av[4], bv[4];
#pragma unroll
      for (int a = 0; a < 4; a++) av[a] = Xs[(r0 + a) * 66 + p];
#pragma unroll
      for (int bq = 0; bq < 4; bq++) bv[bq] = Ys[p * 66 + c0 + bq];
#pragma unroll
      for (int a = 0; a < 4; a++)
#pragma unroll
        for (int bq = 0; bq < 4; bq++) acc[a][bq] += av[a] * bv[bq];
    }
  }
#pragma unroll
  for (int a = 0; a < 4; a++)
#pragma unroll
    for (int bq = 0; bq < 4; bq++)
      Sg[(size_t)((base + w + aa) * 64 + r0 + a) * DD + (base + bb) * 64 + c0 + bq] = acc[a][bq];
}

// level-L launch B: V21(a,b) = -sum_{m<=a} V22(a,m) * T(m,b); -> upper mirror
__global__ void k_vlB(float* sigma, const float* Dinv, int w) {
  __shared__ float Xs[64 * 66], Ys[64 * 66];
  int aa = blockIdx.x / w, bb = blockIdx.x % w;
  int base = blockIdx.y * 2 * w, cls = blockIdx.z;
  float* Sg = sigma + ((size_t)cls << 20);
  int t = threadIdx.x, tx = t & 15, ty = t >> 4;
  int r0 = ty * 4, c0 = tx * 4;
  float acc[4][4] = {};
  for (int m = 0; m <= aa; m++) {
    __syncthreads();
    if (m == aa) {
      const float* Dv = Dinv + ((size_t)(cls * 16 + base + w + aa)) * 4096;
      for (int idx = t; idx < 4096; idx += 256)
        Xs[(idx >> 6) * 66 + (idx & 63)] = Dv[idx];
    } else {
      for (int idx = t; idx < 4096; idx += 256) {
        int r = idx >> 6, p = idx & 63;
        Xs[r * 66 + p] = Sg[(size_t)((base + w + m) * 64 + r) * DD + (base + w + aa) * 64 + p];
      }
    }
    for (int idx = t; idx < 4096; idx += 256) {
      int p = idx >> 6, c = idx & 63;
      Ys[p * 66 + c] = Sg[(size_t)((base + w + m) * 64 + p) * DD + (base + bb) * 64 + c];
    }
    __syncthreads();
#pragma unroll 8
    for (int p = 0; p < 64; p++) {
      float av[4], bv[4];
#pragma unroll
      for (int a = 0; a < 4; a++) av[a] = Xs[(r0 + a) * 66 + p];
#pragma unroll
      for (int bq = 0; bq < 4; bq++) bv[bq] = Ys[p * 66 + c0 + bq];
#pragma unroll
      for (int a = 0; a < 4; a++)
#pragma unroll
        for (int bq = 0; bq < 4; bq++) acc[a][bq] += av[a] * bv[bq];
    }
  }
#pragma unroll
  for (int a = 0; a < 4; a++)
#pragma unroll
    for (int bq = 0; bq < 4; bq++)
      Sg[(size_t)((base + bb) * 64 + r0 + a) * DD + (base + w + aa) * 64 + c0 + bq] = -acc[a][bq];
}

// 2176 blocks: packed-fp16 V-tile copy + fused u-partial (atomicAdd)
__global__ void k_finalize(const float* sigma, const float* Dinv, const float* mu,
                           float* uarr, _Float16* UT) {
  __shared__ float U0[64 * 66];
  __shared__ float CS[4 * 64];
  int jp = blockIdx.x, t = threadIdx.x;
  int cls = jp / 136, tr = jp % 136;
  int nt_, kt_; tri_decode(tr, nt_, kt_);   // nt_ >= kt_
  const float* muc = mu + (size_t)cls * DD;
  _Float16* outp = UT + (size_t)cls * UT_CLS_STRIDE + (size_t)tr * 4096;
  if (kt_ == nt_) {
    const float* Dv = Dinv + ((size_t)(cls * 16 + nt_)) * 4096;
    for (int idx = t; idx < 4096; idx += 256) {
      float w = Dv[idx];
      outp[idx] = (_Float16)w;
      U0[(idx >> 6) * 66 + (idx & 63)] = w;
    }
    __syncthreads();
    int g = t >> 6, r = t & 63;
    float s = 0.f;
    for (int c = g * 16; c < g * 16 + 16; c++)
      s += U0[r * 66 + c] * muc[nt_ * 64 + c];
    CS[g * 64 + r] = s;
    __syncthreads();
    if (g == 0)
      atomicAdd(&uarr[(size_t)cls * DD + nt_ * 64 + r],
                CS[r] + CS[64 + r] + CS[128 + r] + CS[192 + r]);
  } else {
    const float* Sg = sigma + ((size_t)cls << 20);
    for (int i2 = 0; i2 < 16; i2++) {
      int lin = i2 * 256 + t;
      int rr = lin >> 6, cc = lin & 63;
      float v = Sg[(size_t)(kt_ * 64 + rr) * DD + nt_ * 64 + cc];  // V(nt_,kt_)[rr][cc]
      U0[rr * 66 + cc] = v;
      outp[lin] = (_Float16)v;
    }
    __syncthreads();
    int g = t >> 6, np = t & 63;
    float s = 0.f;
    for (int kp = g * 16; kp < g * 16 + 16; kp++)
      s += U0[np * 66 + kp] * muc[kt_ * 64 + kp];
    CS[g * 64 + np] = s;
    __syncthreads();
    if (g == 0)
      atomicAdd(&uarr[(size_t)cls * DD + nt_ * 64 + np],
                CS[np] + CS[64 + np] + CS[128 + np] + CS[192 + np]);
  }
}

// ---------------- predict side ----------------
__global__ void k_xqdots(const float* Xq, const float* mu, float* xq2, float* xqmu,
                         _Float16* XqH) {
  __shared__ float xrow[DD];
  int m = blockIdx.x, t = threadIdx.x;
  for (int i = t; i < 256; i += 256)
    ((float4*)xrow)[i] = ((const float4*)(Xq + (size_t)m * DD))[i];
  __syncthreads();
  for (int i = t; i < DD; i += 256)
    XqH[(size_t)m * DD + i] = (_Float16)xrow[i];
  int wave = t >> 6, lane = t & 63;
  for (int cc = 0; cc < 4; cc++) {
    int c = wave * 4 + cc;
    const float* muc = mu + (size_t)c * DD;
    float s = 0.f;
    for (int j = lane; j < DD; j += 64) s += xrow[j] * muc[j];
    for (int o = 32; o > 0; o >>= 1) s += __shfl_down(s, o, 64);
    if (lane == 0) xqmu[(size_t)m * 16 + c] = s;
  }
  if (wave == 0) {
    float s = 0.f;
    for (int j = lane; j < DD; j += 64) s += xrow[j] * xrow[j];
    for (int o = 32; o > 0; o >>= 1) s += __shfl_down(s, o, 64);
    if (lane == 0) xq2[m] = s;
  }
}

__global__ __launch_bounds__(256) void k_gemmG_mfma(const _Float16* XqH, const _Float16* UT,
                                                    const float* u, float* dout) {
  int mt = blockIdx.x, ct = blockIdx.y, cls = blockIdx.z;
  const _Float16* Uc = UT + (size_t)cls * UT_CLS_STRIDE;
  __shared__ _Float16 As[128 * 40];
  __shared__ _Float16 Bs[128 * 40];
  int t = threadIdx.x;
  int wave = t >> 6, lane = t & 63;
  int wr = wave >> 1, wc = wave & 1;
  int quad = lane >> 4, l15 = lane & 15;
  int m0 = mt * 128, n0 = ct * 128, NT0 = ct * 2;
  floatx4 acc[4][4];
#pragma unroll
  for (int a = 0; a < 4; a++)
#pragma unroll
    for (int b = 0; b < 4; b++) acc[a][b] = (floatx4){0.f, 0.f, 0.f, 0.f};
  int kmax = (ct + 1) * 128;
  for (int kk = 0; kk < kmax; kk += 32) {
    __syncthreads();
#pragma unroll
    for (int i = 0; i < 2; i++) {
      int lin = i * 256 + t;
      int r = lin >> 2, kg = (lin & 3) * 8;
      *(half8*)&As[r * 40 + kg] = *(const half8*)&XqH[(size_t)(m0 + r) * DD + kk + kg];
    }
    int kt = kk >> 6, k0 = kk & 63;
#pragma unroll
    for (int i = 0; i < 2; i++) {
      int lin = i * 256 + t;
      int nl = lin >> 2, kg = (lin & 3) * 8;
      int s = nl >> 6, np = nl & 63;
      int nt = NT0 + s;
      half8 v = {};
      if (kt <= nt)
        v = *(const half8*)&Uc[(size_t)(nt * (nt + 1) / 2 + kt) * 4096 + np * 64 + k0 + kg];
      *(half8*)&Bs[nl * 40 + kg] = v;
    }
    __syncthreads();
    half8 af[4], bf[4];
#pragma unroll
    for (int f = 0; f < 4; f++) {
      af[f] = *(const half8*)&As[(wr * 64 + f * 16 + l15) * 40 + quad * 8];
      bf[f] = *(const half8*)&Bs[(wc * 64 + f * 16 + l15) * 40 + quad * 8];
    }
#pragma unroll
    for (int fi = 0; fi < 4; fi++)
#pragma unroll
      for (int fj = 0; fj < 4; fj++)
        acc[fi][fj] = __builtin_amdgcn_mfma_f32_16x16x32_f16(af[fi], bf[fj], acc[fi][fj], 0, 0, 0);
  }
  float uv[4];
#pragma unroll
  for (int fj = 0; fj < 4; fj++)
    uv[fj] = u[(size_t)cls * DD + n0 + wc * 64 + fj * 16 + l15];
#pragma unroll
  for (int fi = 0; fi < 4; fi++) {
#pragma unroll
    for (int r = 0; r < 4; r++) {
      float p = 0.f;
#pragma unroll
      for (int fj = 0; fj < 4; fj++) {
        float e = acc[fi][fj][r] - uv[fj];
        p += e * e;
      }
      p += __shfl_xor(p, 1, 64);
      p += __shfl_xor(p, 2, 64);
      p += __shfl_xor(p, 4, 64);
      p += __shfl_xor(p, 8, 64);
      if (l15 == 0) {
        int m = m0 + wr * 64 + fi * 16 + quad * 4 + r;
        atomicAdd(&dout[(size_t)m * 16 + cls], p);
      }
    }
  }
}

__global__ void k_logits(const float* xq2, const float* xqmu, const float* mu2,
                         float* dout) {
  size_t idx = (size_t)blockIdx.x * 256 + threadIdx.x;
  int m = (int)(idx >> 4), c = (int)(idx & 15);
  float q1 = dout[idx];
  float q2 = xq2[m] - 2.0f * xqmu[idx] + mu2[c];
  dout[idx] = -(0.9f * q1 + 0.1f * q2);
}

extern "C" void kernel_launch(void* const* d_in, const int* in_sizes, int n_in,
                              void* d_out, int out_size, void* d_ws, size_t ws_size,
                              hipStream_t stream) {
  (void)in_sizes; (void)n_in; (void)out_size; (void)ws_size;
  const float* X  = (const float*)d_in[0];
  const int*   y  = (const int*)d_in[1];
  const float* Xq = (const float*)d_in[2];
  const float* m  = (const float*)d_in[3];
  const float* kappa = (const float*)d_in[4];
  const float* nu = (const float*)d_in[5];
  const float* td = (const float*)d_in[6];
  const float* tl = (const float*)d_in[7];
  float* out = (float*)d_out;
  float* ws = (float*)d_ws;

  short* XTh   = (short*)(ws + OFF_XTH);
  short* XTl   = (short*)(ws + OFF_XTL);
  _Float16* UT = (_Float16*)ws;              // overlays XT planes (dead after syrk)
  float* baseb = ws + OFF_BASE;
  float* sigma = ws + OFF_SIGMA;
  _Float16* XqH = (_Float16*)sigma;          // overlays sigma (dead after finalize)
  float* Dinv  = ws + OFF_DINV;
  float* sums  = ws + OFF_SUMS;
  float* mu    = ws + OFF_MU;
  float* uarr  = ws + OFF_U;
  float* mu2   = ws + OFF_MU2;
  float* xq2   = ws + OFF_XQ2;
  float* xqmu  = ws + OFF_XQMU;
  float* kapnu = ws + OFF_KAPNU;
  float* cf    = ws + OFF_CF;
  float* beta  = ws + OFF_BETA;
  float* invs  = ws + OFF_INVS;
  int* ints      = (int*)(ws + OFF_INTS);
  int* counts    = ints;
  int* offsets   = ints + 16;
  int* cls_of_pt = ints + 32;
  int* order     = ints + 32 + PT_TILES;

  k_scalars<<<1, 256, 0, stream>>>(y, kappa, nu, kapnu, cf, beta, invs,
                                   counts, offsets, cls_of_pt, order,
                                   sums, uarr, out);
  k_gatherT<<<dim3(PT_TILES, 16), 256, 0, stream>>>(X, order, cls_of_pt, XTh, XTl, sums);
  k_mumu2<<<16, 256, 0, stream>>>(sums, m, kapnu, cf, mu, mu2);
  k_base<<<136, 256, 0, stream>>>(td, tl, m, kapnu, baseb);
  k_syrk_mfma<<<16 * 36, 256, 0, stream>>>(XTh, XTl, baseb, mu, beta, invs,
                                           counts, offsets, sigma);
  k_diag0<<<16, 256, 0, stream>>>(sigma, Dinv);
  for (int k = 0; k < 15; k++) {
    int nb = 15 - k;
    int nt = nb * (nb + 1) / 2;
    k_cholstep<<<16 * nt, 256, 0, stream>>>(sigma, Dinv, k);
  }
  k_vl1<<<128, 256, 0, stream>>>(sigma, Dinv);
  for (int L = 2; L <= 4; L++) {
    int w = 1 << (L - 1);
    int ncomb = 8 >> (L - 1);
    k_vlA<<<dim3(w * w, ncomb, 16), 256, 0, stream>>>(sigma, Dinv, w);
    k_vlB<<<dim3(w * w, ncomb, 16), 256, 0, stream>>>(sigma, Dinv, w);
  }
  k_finalize<<<16 * 136, 256, 0, stream>>>(sigma, Dinv, mu, uarr, UT);
  k_xqdots<<<4096, 256, 0, stream>>>(Xq, mu, xq2, xqmu, XqH);
  k_gemmG_mfma<<<dim3(32, 8, 16), 256, 0, stream>>>(XqH, UT, uarr, out);
  k_logits<<<256, 256, 0, stream>>>(xq2, xqmu, mu2, out);
}

// Round 7
// 3061.377 us; speedup vs baseline: 1.2608x; 1.0311x over previous
//
#include <hip/hip_runtime.h>
#include <math.h>

#define DD 1024
#define NP 5120   // padded sample pitch (class offsets padded to 64)
#define PT_TILES 80

typedef _Float16 half8 __attribute__((ext_vector_type(8)));
typedef _Float16 half4 __attribute__((ext_vector_type(4)));
typedef float floatx4 __attribute__((ext_vector_type(4)));
typedef short s16x8 __attribute__((ext_vector_type(8)));

// ---------------- workspace layout (float offsets) ----------------
#define OFF_XTH   ((size_t)0)
#define OFF_XTL   ((size_t)2621440)
#define OFF_BASE  ((size_t)5242880)
#define OFF_SIGMA ((size_t)6291456)    // 16*1024*1024 fp32 (lower: Schur, upper: R panels then V)
#define OFF_DINV  ((size_t)23068672)
#define OFF_SUMS  ((size_t)24117248)
#define OFF_MU    ((size_t)24133632)
#define OFF_U     ((size_t)24150016)
#define OFF_MU2   ((size_t)24166400)
#define OFF_XQ2   ((size_t)24166416)
#define OFF_XQMU  ((size_t)24170512)
#define OFF_KAPNU ((size_t)24236048)
#define OFF_CF    ((size_t)24236056)
#define OFF_BETA  ((size_t)24236072)
#define OFF_INVS  ((size_t)24236088)
#define OFF_INTS  ((size_t)24236104)

#define UT_CLS_STRIDE ((size_t)557056) // 136 tiles * 4096 halves

__device__ __forceinline__ void tri_decode(int b, int& ti, int& tj) {
  int t = 0;
  while ((t + 1) * (t + 2) / 2 <= b) t++;
  ti = t;
  tj = b - t * (t + 1) / 2;
}

__device__ __forceinline__ short f2bf(float f) {
  union { float f; unsigned u; } v; v.f = f;
  unsigned r = v.u + 0x7FFF + ((v.u >> 16) & 1);
  return (short)(r >> 16);
}
__device__ __forceinline__ float bf2f(short b) {
  union { unsigned u; float f; } v; v.u = ((unsigned)(unsigned short)b) << 16; return v.f;
}

__device__ __forceinline__ float reduce256(float v, float* scratch) {
  for (int o = 32; o > 0; o >>= 1) v += __shfl_down(v, o, 64);
  int lane = threadIdx.x & 63, w = threadIdx.x >> 6;
  __syncthreads();
  if (lane == 0) scratch[w] = v;
  __syncthreads();
  return scratch[0] + scratch[1] + scratch[2] + scratch[3];
}

// ---------------- stats ----------------
__global__ void k_scalars(const int* y, const float* kappa, const float* nu,
                          float* kapnu, float* cf, float* beta, float* invs,
                          int* counts, int* offsets, int* cls_of_pt, int* order,
                          float* sums, float* uarr, float* dout) {
  __shared__ int h[16];
  __shared__ int cur[16];
  int t = threadIdx.x;
  if (t < 16) h[t] = 0;
  __syncthreads();
  for (int n = t; n < 4096; n += 256) atomicAdd(&h[y[n]], 1);
  __syncthreads();
  if (t == 0) {
    float kap = fabsf(kappa[0]) + 1e-6f;
    float nu_ = fmaxf(nu[0], 1024.0f - 1.0f + 1e-6f);
    kapnu[0] = kap; kapnu[1] = nu_;
    int off = 0, tile = 0;
    for (int c = 0; c < 16; c++) {
      counts[c] = h[c]; offsets[c] = off; cur[c] = off;
      cf[c] = (float)h[c];
      beta[c] = kap + (float)h[c];
      invs[c] = 1.0f / (nu_ + (float)h[c] + 1024.0f + 2.0f);
      int ntile = ((h[c] + 63) & ~63) >> 6;
      for (int q = 0; q < ntile && tile < PT_TILES; q++) cls_of_pt[tile++] = c;
      off += (h[c] + 63) & ~63;
    }
    while (tile < PT_TILES) cls_of_pt[tile++] = -1;
  }
  for (int i = t; i < NP; i += 256) order[i] = -1;
  for (int i = t; i < 16 * 1024; i += 256) { sums[i] = 0.f; uarr[i] = 0.f; }
  for (int i = t; i < 4096 * 16; i += 256) dout[i] = 0.f;
  __syncthreads();
  for (int n = t; n < 4096; n += 256) {
    int c = y[n];
    int p = atomicAdd(&cur[c], 1);
    order[p] = n;
  }
}

__global__ void k_gatherT(const float* X, const int* order, const int* cls_of_pt,
                          short* XTh, short* XTl, float* sums) {
  int pt = blockIdx.x, dt = blockIdx.y, t = threadIdx.x;
  __shared__ float T[64 * 65];
  __shared__ float CS[4 * 64];
  __shared__ int src[64];
  if (t < 64) src[t] = order[pt * 64 + t];
  __syncthreads();
  for (int i = 0; i < 16; i++) {
    int lin = i * 256 + t;
    int r = lin >> 6, c = lin & 63;
    int s = src[r];
    T[r * 65 + c] = (s >= 0) ? X[(size_t)s * DD + dt * 64 + c] : 0.f;
  }
  __syncthreads();
  for (int i = 0; i < 16; i++) {
    int lin = i * 256 + t;
    int d = lin >> 6, p = lin & 63;
    float v = T[p * 65 + d];
    short hi = f2bf(v);
    float lov = v - bf2f(hi);
    size_t addr = (size_t)(dt * 64 + d) * NP + pt * 64 + p;
    XTh[addr] = hi;
    XTl[addr] = f2bf(lov);
  }
  int cls = cls_of_pt[pt];
  if (cls < 0) return;
  int g = t >> 6, d = t & 63;
  float s = 0.f;
  for (int p = g * 16; p < g * 16 + 16; p++) s += T[p * 65 + d];
  CS[g * 64 + d] = s;
  __syncthreads();
  if (g == 0)
    atomicAdd(&sums[(size_t)cls * DD + dt * 64 + d],
              CS[d] + CS[64 + d] + CS[128 + d] + CS[192 + d]);
}

__global__ void k_mumu2(const float* sums, const float* m, const float* kapnu,
                        const float* cf, float* mu, float* mu2) {
  __shared__ float scratch[4];
  int c = blockIdx.x, t = threadIdx.x;
  float kap = kapnu[0];
  float denom = 1.0f / (kap + cf[c]);
  float s2 = 0.f;
  for (int j = t; j < DD; j += 256) {
    float v = (kap * m[j] + sums[(size_t)c * DD + j]) * denom;
    mu[(size_t)c * DD + j] = v;
    s2 += v * v;
  }
  float tot = reduce256(s2, scratch);
  if (t == 0) mu2[c] = tot;
}

__device__ __forceinline__ float lval(const float* td, const float* tl, int i, int j) {
  if (i == j) return fabsf(td[i]);
  if (i > j) return tl[(size_t)i * DD + j];
  return 0.f;
}

__global__ void k_base(const float* td, const float* tl, const float* m,
                       const float* kapnu, float* base) {
  int ti, tj; tri_decode(blockIdx.x, ti, tj);
  __shared__ float Ta[16][65], Tb[16][65];
  int t = threadIdx.x, tx = t & 15, ty = t >> 4;
  int r0 = ty * 4, c0 = tx * 4;
  float acc[4][4] = {};
  int kmax = (tj + 1) * 64;
  for (int kk = 0; kk < kmax; kk += 16) {
    __syncthreads();
    for (int idx = t; idx < 64 * 16; idx += 256) {
      int r = idx >> 4, p = idx & 15;
      Ta[p][r] = lval(td, tl, ti * 64 + r, kk + p);
      Tb[p][r] = lval(td, tl, tj * 64 + r, kk + p);
    }
    __syncthreads();
#pragma unroll
    for (int p = 0; p < 16; p++) {
      float av[4], bv[4];
#pragma unroll
      for (int a = 0; a < 4; a++) av[a] = Ta[p][r0 + a];
#pragma unroll
      for (int b = 0; b < 4; b++) bv[b] = Tb[p][c0 + b];
#pragma unroll
      for (int a = 0; a < 4; a++)
#pragma unroll
        for (int b = 0; b < 4; b++) acc[a][b] += av[a] * bv[b];
    }
  }
  float kap = kapnu[0];
#pragma unroll
  for (int a = 0; a < 4; a++)
#pragma unroll
    for (int b = 0; b < 4; b++) {
      int gi = ti * 64 + r0 + a, gj = tj * 64 + c0 + b;
      base[(size_t)gi * DD + gj] = acc[a][b] + kap * m[gi] * m[gj];
    }
}

__global__ __launch_bounds__(256) void k_syrk_mfma(const short* XTh, const short* XTl,
                                                   const float* base, const float* mu,
                                                   const float* beta, const float* invs,
                                                   const int* counts, const int* offsets,
                                                   float* sigma) {
  int bb = blockIdx.x;
  int cls = bb / 36, tr = bb % 36;
  int ti, tj; tri_decode(tr, ti, tj);
  int cnt = counts[cls], off = offsets[cls];
  float* Sg = sigma + ((size_t)cls << 20);
  const float* muc = mu + (size_t)cls * DD;
  __shared__ short Ah[128 * 40], Al[128 * 40], Bh[128 * 40], Bl[128 * 40];
  int t = threadIdx.x;
  int wave = t >> 6, lane = t & 63;
  int wr = wave >> 1, wc = wave & 1;
  int quad = lane >> 4, l15 = lane & 15;
  int i0 = ti * 128, j0 = tj * 128;
  bool same = (ti == tj);
  floatx4 acc[4][4];
#pragma unroll
  for (int a = 0; a < 4; a++)
#pragma unroll
    for (int b = 0; b < 4; b++) acc[a][b] = (floatx4){0.f, 0.f, 0.f, 0.f};
  for (int nn = 0; nn < cnt; nn += 32) {
    __syncthreads();
#pragma unroll
    for (int r = 0; r < 2; r++) {
      int lin = r * 256 + t;
      int row = lin >> 2, kg = (lin & 3) << 3;
      size_t sA = (size_t)(i0 + row) * NP + off + nn + kg;
      *(s16x8*)&Ah[row * 40 + kg] = *(const s16x8*)&XTh[sA];
      *(s16x8*)&Al[row * 40 + kg] = *(const s16x8*)&XTl[sA];
      if (!same) {
        size_t sB = (size_t)(j0 + row) * NP + off + nn + kg;
        *(s16x8*)&Bh[row * 40 + kg] = *(const s16x8*)&XTh[sB];
        *(s16x8*)&Bl[row * 40 + kg] = *(const s16x8*)&XTl[sB];
      }
    }
    __syncthreads();
    const short* PBh = same ? Ah : Bh;
    const short* PBl = same ? Al : Bl;
    s16x8 ah[4], al[4], bh[4], bl[4];
#pragma unroll
    for (int f = 0; f < 4; f++) {
      ah[f] = *(const s16x8*)&Ah[(wr * 64 + f * 16 + l15) * 40 + quad * 8];
      al[f] = *(const s16x8*)&Al[(wr * 64 + f * 16 + l15) * 40 + quad * 8];
      bh[f] = *(const s16x8*)&PBh[(wc * 64 + f * 16 + l15) * 40 + quad * 8];
      bl[f] = *(const s16x8*)&PBl[(wc * 64 + f * 16 + l15) * 40 + quad * 8];
    }
#pragma unroll
    for (int fi = 0; fi < 4; fi++)
#pragma unroll
      for (int fj = 0; fj < 4; fj++) {
        acc[fi][fj] = __builtin_amdgcn_mfma_f32_16x16x32_bf16(ah[fi], bh[fj], acc[fi][fj], 0, 0, 0);
        acc[fi][fj] = __builtin_amdgcn_mfma_f32_16x16x32_bf16(ah[fi], bl[fj], acc[fi][fj], 0, 0, 0);
        acc[fi][fj] = __builtin_amdgcn_mfma_f32_16x16x32_bf16(al[fi], bh[fj], acc[fi][fj], 0, 0, 0);
      }
  }
  float bet = beta[cls], isc = invs[cls];
#pragma unroll
  for (int fi = 0; fi < 4; fi++)
#pragma unroll
    for (int fj = 0; fj < 4; fj++)
#pragma unroll
      for (int reg = 0; reg < 4; reg++) {
        int gi = i0 + wr * 64 + fi * 16 + quad * 4 + reg;
        int gj = j0 + wc * 64 + fj * 16 + l15;
        float v = acc[fi][fj][reg] + base[(size_t)gi * DD + gj] - bet * muc[gi] * muc[gj];
        Sg[(size_t)gi * DD + gj] = v * isc;
      }
}

// ---------------- factorization ----------------
// LDL^T elimination (1 sync/step) + end scaling + STEP-PARALLEL triangular
// inversion (4 threads/column). Replaces the divergent serial version that
// cost ~100+ us per launch (R6 post-mortem).
__device__ void chol_from_lds(float* Sg, float* Dinv, int cls, int k, int t,
                              float* A, float* W) {
  __shared__ float sdiag[64];
  __shared__ float CSum[4 * 64];
  // elimination: A[r][c] -= A[r][j]*A[c][j]/d_j  (lower half only)
  for (int j = 0; j < 63; j++) {
    __syncthreads();
    float rd = 1.0f / A[j * 65 + j];
    for (int idx = t; idx < 4096; idx += 256) {
      int r = idx >> 6, c = idx & 63;
      if (c > j && c <= r) A[r * 65 + c] -= A[r * 65 + j] * A[c * 65 + j] * rd;
    }
  }
  __syncthreads();
  if (t < 64) sdiag[t] = 1.0f / sqrtf(A[t * 65 + t]);   // = 1/L[t][t]
  __syncthreads();
  // scale: L[r][c] = A[r][c]/sqrt(d_c) for r>=c (diag -> sqrt(d))
  for (int idx = t; idx < 4096; idx += 256) {
    int r = idx >> 6, c = idx & 63;
    if (r >= c) A[r * 65 + c] *= sdiag[c];
    W[r * 65 + c] = 0.f;
  }
  __syncthreads();
  if (t < 64) W[t * 65 + t] = sdiag[t];
  __syncthreads();
  // W = inv(L): row steps, 4 threads per column
  int jcol = t & 63, g = t >> 6;
  for (int i = 1; i < 64; i++) {
    float s = 0.f;
    if (jcol < i) {
      int k0 = g * 16; if (jcol > k0) k0 = jcol;
      int k1 = g * 16 + 16; if (i < k1) k1 = i;
      for (int kk = k0; kk < k1; kk++) s += A[i * 65 + kk] * W[kk * 65 + jcol];
    }
    CSum[g * 64 + jcol] = s;
    __syncthreads();
    if (g == 0 && jcol < i) {
      float tot = CSum[jcol] + CSum[64 + jcol] + CSum[128 + jcol] + CSum[192 + jcol];
      W[i * 65 + jcol] = -sdiag[i] * tot;
    }
    __syncthreads();
  }
  for (int idx = t; idx < 4096; idx += 256) {
    int r = idx >> 6, c = idx & 63;
    Sg[(size_t)(k * 64 + r) * DD + k * 64 + c] = (c <= r) ? A[r * 65 + c] : 0.f;
    Dinv[((size_t)(cls * 16 + k)) * 4096 + idx] = W[r * 65 + c];
  }
}

__global__ void k_diag0(float* sigma, float* Dinv) {
  __shared__ float A[64 * 65], W[64 * 65];
  int cls = blockIdx.x, t = threadIdx.x;
  float* Sg = sigma + ((size_t)cls << 20);
  for (int idx = t; idx < 4096; idx += 256) {
    int r = idx >> 6, c = idx & 63;
    A[r * 65 + c] = Sg[(size_t)r * DD + c];
  }
  __syncthreads();
  chol_from_lds(Sg, Dinv, cls, 0, t, A, W);
}

// merged step k: panels P_i = A(i,k)*W_k^T in LDS; b_==0 blocks persist panel
// to the UPPER mirror; trailing S(it,jt) -= P_i P_j^T; special block factors
// diag k+1 in LDS.
__global__ void k_cholstep(float* sigma, float* Dinv, int k) {
  __shared__ float B0[64 * 65], B1[64 * 65], B2[64 * 65];
  int b = blockIdx.x, t = threadIdx.x;
  int tx = t & 15, ty = t >> 4;
  int r0 = ty * 4, c0 = tx * 4;
  int nb = 15 - k;
  int nt = nb * (nb + 1) / 2;
  int cls, a_, b_;
  bool special = (b < 16);
  if (special) { cls = b; a_ = 0; b_ = 0; }
  else {
    int jp = b - 16;
    cls = jp / (nt - 1);
    int s = jp % (nt - 1) + 1;
    tri_decode(s, a_, b_);
  }
  int it = k + 1 + a_, jt = k + 1 + b_;
  bool same = (it == jt);
  float* Sg = sigma + ((size_t)cls << 20);
  for (int idx = t; idx < 4096; idx += 256) {
    int r = idx >> 6, p = idx & 63;
    B0[r * 65 + p] = Dinv[((size_t)(cls * 16 + k)) * 4096 + idx];
    B1[r * 65 + p] = Sg[(size_t)(it * 64 + r) * DD + k * 64 + p];
    if (!same) B2[r * 65 + p] = Sg[(size_t)(jt * 64 + r) * DD + k * 64 + p];
  }
  __syncthreads();
  float a1[4][4] = {}, a2[4][4] = {};
#pragma unroll 8
  for (int p = 0; p < 64; p++) {
    float av[4], bv[4];
#pragma unroll
    for (int a = 0; a < 4; a++) av[a] = B1[(r0 + a) * 65 + p];
#pragma unroll
    for (int bq = 0; bq < 4; bq++) bv[bq] = B0[(c0 + bq) * 65 + p];
#pragma unroll
    for (int a = 0; a < 4; a++)
#pragma unroll
      for (int bq = 0; bq < 4; bq++) a1[a][bq] += av[a] * bv[bq];
  }
  if (!same) {
#pragma unroll 8
    for (int p = 0; p < 64; p++) {
      float av[4], bv[4];
#pragma unroll
      for (int a = 0; a < 4; a++) av[a] = B2[(r0 + a) * 65 + p];
#pragma unroll
      for (int bq = 0; bq < 4; bq++) bv[bq] = B0[(c0 + bq) * 65 + p];
#pragma unroll
      for (int a = 0; a < 4; a++)
#pragma unroll
        for (int bq = 0; bq < 4; bq++) a2[a][bq] += av[a] * bv[bq];
    }
  }
  __syncthreads();
#pragma unroll
  for (int a = 0; a < 4; a++)
#pragma unroll
    for (int bq = 0; bq < 4; bq++) {
      B1[(r0 + a) * 65 + c0 + bq] = a1[a][bq];
      if (!same) B2[(r0 + a) * 65 + c0 + bq] = a2[a][bq];
    }
  if (b_ == 0) {
#pragma unroll
    for (int a = 0; a < 4; a++) {
      float4 v = make_float4(a1[a][0], a1[a][1], a1[a][2], a1[a][3]);
      *(float4*)&Sg[(size_t)(k * 64 + r0 + a) * DD + it * 64 + c0] = v;
    }
  }
  __syncthreads();
  float* PB = same ? B1 : B2;
  float a3[4][4] = {};
#pragma unroll 8
  for (int p = 0; p < 64; p++) {
    float av[4], bv[4];
#pragma unroll
    for (int a = 0; a < 4; a++) av[a] = B1[(r0 + a) * 65 + p];
#pragma unroll
    for (int bq = 0; bq < 4; bq++) bv[bq] = PB[(c0 + bq) * 65 + p];
#pragma unroll
    for (int a = 0; a < 4; a++)
#pragma unroll
      for (int bq = 0; bq < 4; bq++) a3[a][bq] += av[a] * bv[bq];
  }
  if (!special) {
#pragma unroll
    for (int a = 0; a < 4; a++)
#pragma unroll
      for (int bq = 0; bq < 4; bq++) {
        size_t addr = (size_t)(it * 64 + r0 + a) * DD + jt * 64 + c0 + bq;
        Sg[addr] -= a3[a][bq];
      }
    return;
  }
  __syncthreads();
#pragma unroll
  for (int a = 0; a < 4; a++)
#pragma unroll
    for (int bq = 0; bq < 4; bq++) {
      size_t addr = (size_t)(it * 64 + r0 + a) * DD + jt * 64 + c0 + bq;
      B0[(r0 + a) * 65 + c0 + bq] = Sg[addr] - a3[a][bq];
    }
  __syncthreads();
  chol_from_lds(Sg, Dinv, cls, k + 1, t, B0, B2);
}

// level-1 V combine (width 64->128), fully in-LDS: V21 = -W1 * R * W0
__global__ void k_vl1(float* sigma, const float* Dinv) {
  __shared__ float Rl[64 * 65], W0s[64 * 65], W1s[64 * 65], Ts[64 * 65];
  int b = blockIdx.x, t = threadIdx.x;
  int cls = b >> 3, i = b & 7;
  int t0 = 2 * i, t1 = 2 * i + 1;
  float* Sg = sigma + ((size_t)cls << 20);
  int tx = t & 15, ty = t >> 4;
  int r0 = ty * 4, c0 = tx * 4;
  for (int idx = t; idx < 4096; idx += 256) {
    int r = idx >> 6, p = idx & 63;
    Rl[r * 65 + p] = Sg[(size_t)(t0 * 64 + r) * DD + t1 * 64 + p];
    W0s[r * 65 + p] = Dinv[((size_t)(cls * 16 + t0)) * 4096 + idx];
    W1s[r * 65 + p] = Dinv[((size_t)(cls * 16 + t1)) * 4096 + idx];
  }
  __syncthreads();
  float aT[4][4] = {};
#pragma unroll 8
  for (int p = 0; p < 64; p++) {
    float av[4], bv[4];
#pragma unroll
    for (int a = 0; a < 4; a++) av[a] = Rl[(r0 + a) * 65 + p];
#pragma unroll
    for (int bq = 0; bq < 4; bq++) bv[bq] = W0s[p * 65 + c0 + bq];
#pragma unroll
    for (int a = 0; a < 4; a++)
#pragma unroll
      for (int bq = 0; bq < 4; bq++) aT[a][bq] += av[a] * bv[bq];
  }
  __syncthreads();
#pragma unroll
  for (int a = 0; a < 4; a++)
#pragma unroll
    for (int bq = 0; bq < 4; bq++) Ts[(r0 + a) * 65 + c0 + bq] = aT[a][bq];
  __syncthreads();
  float aV[4][4] = {};
#pragma unroll 8
  for (int p = 0; p < 64; p++) {
    float av[4], bv[4];
#pragma unroll
    for (int a = 0; a < 4; a++) av[a] = W1s[(r0 + a) * 65 + p];
#pragma unroll
    for (int bq = 0; bq < 4; bq++) bv[bq] = Ts[p * 65 + c0 + bq];
#pragma unroll
    for (int a = 0; a < 4; a++)
#pragma unroll
      for (int bq = 0; bq < 4; bq++) aV[a][bq] += av[a] * bv[bq];
  }
#pragma unroll
  for (int a = 0; a < 4; a++)
#pragma unroll
    for (int bq = 0; bq < 4; bq++)
      Sg[(size_t)(t0 * 64 + r0 + a) * DD + t1 * 64 + c0 + bq] = -aV[a][bq];
}

// level-L launch A: T(a,b) = sum_m R21(a,m) * V11(m,b); T -> lower scratch
__global__ void k_vlA(float* sigma, const float* Dinv, int w) {
  __shared__ float Xs[64 * 65], Ys[64 * 65];
  int aa = blockIdx.x / w, bb = blockIdx.x % w;
  int base = blockIdx.y * 2 * w, cls = blockIdx.z;
  float* Sg = sigma + ((size_t)cls << 20);
  int t = threadIdx.x, tx = t & 15, ty = t >> 4;
  int r0 = ty * 4, c0 = tx * 4;
  float acc[4][4] = {};
  for (int m = bb; m < w; m++) {
    __syncthreads();
    for (int idx = t; idx < 4096; idx += 256) {
      int r = idx >> 6, p = idx & 63;
      Xs[r * 65 + p] = Sg[(size_t)((base + m) * 64 + r) * DD + (base + w + aa) * 64 + p];
    }
    if (m == bb) {
      const float* Dv = Dinv + ((size_t)(cls * 16 + base + bb)) * 4096;
      for (int idx = t; idx < 4096; idx += 256)
        Ys[(idx >> 6) * 65 + (idx & 63)] = Dv[idx];
    } else {
      for (int idx = t; idx < 4096; idx += 256) {
        int p = idx >> 6, c = idx & 63;
        Ys[p * 65 + c] = Sg[(size_t)((base + bb) * 64 + p) * DD + (base + m) * 64 + c];
      }
    }
    __syncthreads();
#pragma unroll 8
    for (int p = 0; p < 64; p++) {
      float av[4], bv[4];
#pragma unroll
      for (int a = 0; a < 4; a++) av[a] = Xs[(r0 + a) * 65 + p];
#pragma unroll
      for (int bq = 0; bq < 4; bq++) bv[bq] = Ys[p * 65 + c0 + bq];
#pragma unroll
      for (int a = 0; a < 4; a++)
#pragma unroll
        for (int bq = 0; bq < 4; bq++) acc[a][bq] += av[a] * bv[bq];
    }
  }
#pragma unroll
  for (int a = 0; a < 4; a++)
#pragma unroll
    for (int bq = 0; bq < 4; bq++)
      Sg[(size_t)((base + w + aa) * 64 + r0 + a) * DD + (base + bb) * 64 + c0 + bq] = acc[a][bq];
}

// level-L launch B: V21(a,b) = -sum_{m<=a} V22(a,m) * T(m,b); -> upper mirror
__global__ void k_vlB(float* sigma, const float* Dinv, int w) {
  __shared__ float Xs[64 * 65], Ys[64 * 65];
  int aa = blockIdx.x / w, bb = blockIdx.x % w;
  int base = blockIdx.y * 2 * w, cls = blockIdx.z;
  float* Sg = sigma + ((size_t)cls << 20);
  int t = threadIdx.x, tx = t & 15, ty = t >> 4;
  int r0 = ty * 4, c0 = tx * 4;
  float acc[4][4] = {};
  for (int m = 0; m <= aa; m++) {
    __syncthreads();
    if (m == aa) {
      const float* Dv = Dinv + ((size_t)(cls * 16 + base + w + aa)) * 4096;
      for (int idx = t; idx < 4096; idx += 256)
        Xs[(idx >> 6) * 65 + (idx & 63)] = Dv[idx];
    } else {
      for (int idx = t; idx < 4096; idx += 256) {
        int r = idx >> 6, p = idx & 63;
        Xs[r * 65 + p] = Sg[(size_t)((base + w + m) * 64 + r) * DD + (base + w + aa) * 64 + p];
      }
    }
    for (int idx = t; idx < 4096; idx += 256) {
      int p = idx >> 6, c = idx & 63;
      Ys[p * 65 + c] = Sg[(size_t)((base + w + m) * 64 + p) * DD + (base + bb) * 64 + c];
    }
    __syncthreads();
#pragma unroll 8
    for (int p = 0; p < 64; p++) {
      float av[4], bv[4];
#pragma unroll
      for (int a = 0; a < 4; a++) av[a] = Xs[(r0 + a) * 65 + p];
#pragma unroll
      for (int bq = 0; bq < 4; bq++) bv[bq] = Ys[p * 65 + c0 + bq];
#pragma unroll
      for (int a = 0; a < 4; a++)
#pragma unroll
        for (int bq = 0; bq < 4; bq++) acc[a][bq] += av[a] * bv[bq];
    }
  }
#pragma unroll
  for (int a = 0; a < 4; a++)
#pragma unroll
    for (int bq = 0; bq < 4; bq++)
      Sg[(size_t)((base + bb) * 64 + r0 + a) * DD + (base + w + aa) * 64 + c0 + bq] = -acc[a][bq];
}

// 2176 blocks: packed-fp16 V-tile copy + fused u-partial (atomicAdd)
__global__ void k_finalize(const float* sigma, const float* Dinv, const float* mu,
                           float* uarr, _Float16* UT) {
  __shared__ float U0[64 * 65];
  __shared__ float CS[4 * 64];
  int jp = blockIdx.x, t = threadIdx.x;
  int cls = jp / 136, tr = jp % 136;
  int nt_, kt_; tri_decode(tr, nt_, kt_);   // nt_ >= kt_
  const float* muc = mu + (size_t)cls * DD;
  _Float16* outp = UT + (size_t)cls * UT_CLS_STRIDE + (size_t)tr * 4096;
  if (kt_ == nt_) {
    const float* Dv = Dinv + ((size_t)(cls * 16 + nt_)) * 4096;
    for (int idx = t; idx < 4096; idx += 256) {
      float w = Dv[idx];
      outp[idx] = (_Float16)w;
      U0[(idx >> 6) * 65 + (idx & 63)] = w;
    }
    __syncthreads();
    int g = t >> 6, r = t & 63;
    float s = 0.f;
    for (int c = g * 16; c < g * 16 + 16; c++)
      s += U0[r * 65 + c] * muc[nt_ * 64 + c];
    CS[g * 64 + r] = s;
    __syncthreads();
    if (g == 0)
      atomicAdd(&uarr[(size_t)cls * DD + nt_ * 64 + r],
                CS[r] + CS[64 + r] + CS[128 + r] + CS[192 + r]);
  } else {
    const float* Sg = sigma + ((size_t)cls << 20);
    for (int i2 = 0; i2 < 16; i2++) {
      int lin = i2 * 256 + t;
      int rr = lin >> 6, cc = lin & 63;
      float v = Sg[(size_t)(kt_ * 64 + rr) * DD + nt_ * 64 + cc];  // V(nt_,kt_)[rr][cc]
      U0[rr * 65 + cc] = v;
      outp[lin] = (_Float16)v;
    }
    __syncthreads();
    int g = t >> 6, np = t & 63;
    float s = 0.f;
    for (int kp = g * 16; kp < g * 16 + 16; kp++)
      s += U0[np * 65 + kp] * muc[kt_ * 64 + kp];
    CS[g * 64 + np] = s;
    __syncthreads();
    if (g == 0)
      atomicAdd(&uarr[(size_t)cls * DD + nt_ * 64 + np],
                CS[np] + CS[64 + np] + CS[128 + np] + CS[192 + np]);
  }
}

// ---------------- predict side ----------------
__global__ void k_xqdots(const float* Xq, const float* mu, float* xq2, float* xqmu,
                         _Float16* XqH) {
  __shared__ float xrow[DD];
  int m = blockIdx.x, t = threadIdx.x;
  for (int i = t; i < 256; i += 256)
    ((float4*)xrow)[i] = ((const float4*)(Xq + (size_t)m * DD))[i];
  __syncthreads();
  for (int i = t; i < DD; i += 256)
    XqH[(size_t)m * DD + i] = (_Float16)xrow[i];
  int wave = t >> 6, lane = t & 63;
  for (int cc = 0; cc < 4; cc++) {
    int c = wave * 4 + cc;
    const float* muc = mu + (size_t)c * DD;
    float s = 0.f;
    for (int j = lane; j < DD; j += 64) s += xrow[j] * muc[j];
    for (int o = 32; o > 0; o >>= 1) s += __shfl_down(s, o, 64);
    if (lane == 0) xqmu[(size_t)m * 16 + c] = s;
  }
  if (wave == 0) {
    float s = 0.f;
    for (int j = lane; j < DD; j += 64) s += xrow[j] * xrow[j];
    for (int o = 32; o > 0; o >>= 1) s += __shfl_down(s, o, 64);
    if (lane == 0) xq2[m] = s;
  }
}

__global__ __launch_bounds__(256) void k_gemmG_mfma(const _Float16* XqH, const _Float16* UT,
                                                    const float* u, float* dout) {
  int mt = blockIdx.x, ct = blockIdx.y, cls = blockIdx.z;
  const _Float16* Uc = UT + (size_t)cls * UT_CLS_STRIDE;
  __shared__ _Float16 As[128 * 40];
  __shared__ _Float16 Bs[128 * 40];
  int t = threadIdx.x;
  int wave = t >> 6, lane = t & 63;
  int wr = wave >> 1, wc = wave & 1;
  int quad = lane >> 4, l15 = lane & 15;
  int m0 = mt * 128, n0 = ct * 128, NT0 = ct * 2;
  floatx4 acc[4][4];
#pragma unroll
  for (int a = 0; a < 4; a++)
#pragma unroll
    for (int b = 0; b < 4; b++) acc[a][b] = (floatx4){0.f, 0.f, 0.f, 0.f};
  int kmax = (ct + 1) * 128;
  for (int kk = 0; kk < kmax; kk += 32) {
    __syncthreads();
#pragma unroll
    for (int i = 0; i < 2; i++) {
      int lin = i * 256 + t;
      int r = lin >> 2, kg = (lin & 3) * 8;
      *(half8*)&As[r * 40 + kg] = *(const half8*)&XqH[(size_t)(m0 + r) * DD + kk + kg];
    }
    int kt = kk >> 6, k0 = kk & 63;
#pragma unroll
    for (int i = 0; i < 2; i++) {
      int lin = i * 256 + t;
      int nl = lin >> 2, kg = (lin & 3) * 8;
      int s = nl >> 6, np = nl & 63;
      int nt = NT0 + s;
      half8 v = {};
      if (kt <= nt)
        v = *(const half8*)&Uc[(size_t)(nt * (nt + 1) / 2 + kt) * 4096 + np * 64 + k0 + kg];
      *(half8*)&Bs[nl * 40 + kg] = v;
    }
    __syncthreads();
    half8 af[4], bf[4];
#pragma unroll
    for (int f = 0; f < 4; f++) {
      af[f] = *(const half8*)&As[(wr * 64 + f * 16 + l15) * 40 + quad * 8];
      bf[f] = *(const half8*)&Bs[(wc * 64 + f * 16 + l15) * 40 + quad * 8];
    }
#pragma unroll
    for (int fi = 0; fi < 4; fi++)
#pragma unroll
      for (int fj = 0; fj < 4; fj++)
        acc[fi][fj] = __builtin_amdgcn_mfma_f32_16x16x32_f16(af[fi], bf[fj], acc[fi][fj], 0, 0, 0);
  }
  float uv[4];
#pragma unroll
  for (int fj = 0; fj < 4; fj++)
    uv[fj] = u[(size_t)cls * DD + n0 + wc * 64 + fj * 16 + l15];
#pragma unroll
  for (int fi = 0; fi < 4; fi++) {
#pragma unroll
    for (int r = 0; r < 4; r++) {
      float p = 0.f;
#pragma unroll
      for (int fj = 0; fj < 4; fj++) {
        float e = acc[fi][fj][r] - uv[fj];
        p += e * e;
      }
      p += __shfl_xor(p, 1, 64);
      p += __shfl_xor(p, 2, 64);
      p += __shfl_xor(p, 4, 64);
      p += __shfl_xor(p, 8, 64);
      if (l15 == 0) {
        int m = m0 + wr * 64 + fi * 16 + quad * 4 + r;
        atomicAdd(&dout[(size_t)m * 16 + cls], p);
      }
    }
  }
}

__global__ void k_logits(const float* xq2, const float* xqmu, const float* mu2,
                         float* dout) {
  size_t idx = (size_t)blockIdx.x * 256 + threadIdx.x;
  int m = (int)(idx >> 4), c = (int)(idx & 15);
  float q1 = dout[idx];
  float q2 = xq2[m] - 2.0f * xqmu[idx] + mu2[c];
  dout[idx] = -(0.9f * q1 + 0.1f * q2);
}

extern "C" void kernel_launch(void* const* d_in, const int* in_sizes, int n_in,
                              void* d_out, int out_size, void* d_ws, size_t ws_size,
                              hipStream_t stream) {
  (void)in_sizes; (void)n_in; (void)out_size; (void)ws_size;
  const float* X  = (const float*)d_in[0];
  const int*   y  = (const int*)d_in[1];
  const float* Xq = (const float*)d_in[2];
  const float* m  = (const float*)d_in[3];
  const float* kappa = (const float*)d_in[4];
  const float* nu = (const float*)d_in[5];
  const float* td = (const float*)d_in[6];
  const float* tl = (const float*)d_in[7];
  float* out = (float*)d_out;
  float* ws = (float*)d_ws;

  short* XTh   = (short*)(ws + OFF_XTH);
  short* XTl   = (short*)(ws + OFF_XTL);
  _Float16* UT = (_Float16*)ws;              // overlays XT planes (dead after syrk)
  float* baseb = ws + OFF_BASE;
  float* sigma = ws + OFF_SIGMA;
  _Float16* XqH = (_Float16*)sigma;          // overlays sigma (dead after finalize)
  float* Dinv  = ws + OFF_DINV;
  float* sums  = ws + OFF_SUMS;
  float* mu    = ws + OFF_MU;
  float* uarr  = ws + OFF_U;
  float* mu2   = ws + OFF_MU2;
  float* xq2   = ws + OFF_XQ2;
  float* xqmu  = ws + OFF_XQMU;
  float* kapnu = ws + OFF_KAPNU;
  float* cf    = ws + OFF_CF;
  float* beta  = ws + OFF_BETA;
  float* invs  = ws + OFF_INVS;
  int* ints      = (int*)(ws + OFF_INTS);
  int* counts    = ints;
  int* offsets   = ints + 16;
  int* cls_of_pt = ints + 32;
  int* order     = ints + 32 + PT_TILES;

  k_scalars<<<1, 256, 0, stream>>>(y, kappa, nu, kapnu, cf, beta, invs,
                                   counts, offsets, cls_of_pt, order,
                                   sums, uarr, out);
  k_gatherT<<<dim3(PT_TILES, 16), 256, 0, stream>>>(X, order, cls_of_pt, XTh, XTl, sums);
  k_mumu2<<<16, 256, 0, stream>>>(sums, m, kapnu, cf, mu, mu2);
  k_base<<<136, 256, 0, stream>>>(td, tl, m, kapnu, baseb);
  k_syrk_mfma<<<16 * 36, 256, 0, stream>>>(XTh, XTl, baseb, mu, beta, invs,
                                           counts, offsets, sigma);
  k_diag0<<<16, 256, 0, stream>>>(sigma, Dinv);
  for (int k = 0; k < 15; k++) {
    int nb = 15 - k;
    int nt = nb * (nb + 1) / 2;
    k_cholstep<<<16 * nt, 256, 0, stream>>>(sigma, Dinv, k);
  }
  k_vl1<<<128, 256, 0, stream>>>(sigma, Dinv);
  for (int L = 2; L <= 4; L++) {
    int w = 1 << (L - 1);
    int ncomb = 8 >> (L - 1);
    k_vlA<<<dim3(w * w, ncomb, 16), 256, 0, stream>>>(sigma, Dinv, w);
    k_vlB<<<dim3(w * w, ncomb, 16), 256, 0, stream>>>(sigma, Dinv, w);
  }
  k_finalize<<<16 * 136, 256, 0, stream>>>(sigma, Dinv, mu, uarr, UT);
  k_xqdots<<<4096, 256, 0, stream>>>(Xq, mu, xq2, xqmu, XqH);
  k_gemmG_mfma<<<dim3(32, 8, 16), 256, 0, stream>>>(XqH, UT, uarr, out);
  k_logits<<<256, 256, 0, stream>>>(xq2, xqmu, mu2, out);
}

// Round 8
// 2975.346 us; speedup vs baseline: 1.2973x; 1.0289x over previous
//
#include <hip/hip_runtime.h>
#include <math.h>

#define DD 1024
#define NP 5120   // padded sample pitch (class offsets padded to 64)
#define PT_TILES 80
#define TS 68     // fp32 LDS tile stride (float4-aligned, bank-step 4 => 2-way/free)

typedef _Float16 half8 __attribute__((ext_vector_type(8)));
typedef _Float16 half4 __attribute__((ext_vector_type(4)));
typedef float floatx4 __attribute__((ext_vector_type(4)));
typedef short s16x8 __attribute__((ext_vector_type(8)));

// ---------------- workspace layout (float offsets) ----------------
#define OFF_XTH   ((size_t)0)
#define OFF_XTL   ((size_t)2621440)
#define OFF_BASE  ((size_t)5242880)
#define OFF_SIGMA ((size_t)6291456)    // 16*1024*1024 fp32 (lower: Schur, upper: R panels then V)
#define OFF_DINV  ((size_t)23068672)
#define OFF_SUMS  ((size_t)24117248)
#define OFF_MU    ((size_t)24133632)
#define OFF_U     ((size_t)24150016)
#define OFF_MU2   ((size_t)24166400)
#define OFF_XQ2   ((size_t)24166416)
#define OFF_XQMU  ((size_t)24170512)
#define OFF_KAPNU ((size_t)24236048)
#define OFF_CF    ((size_t)24236056)
#define OFF_BETA  ((size_t)24236072)
#define OFF_INVS  ((size_t)24236088)
#define OFF_INTS  ((size_t)24236104)

#define UT_CLS_STRIDE ((size_t)557056) // 136 tiles * 4096 halves

__device__ __forceinline__ void tri_decode(int b, int& ti, int& tj) {
  int t = 0;
  while ((t + 1) * (t + 2) / 2 <= b) t++;
  ti = t;
  tj = b - t * (t + 1) / 2;
}

__device__ __forceinline__ short f2bf(float f) {
  union { float f; unsigned u; } v; v.f = f;
  unsigned r = v.u + 0x7FFF + ((v.u >> 16) & 1);
  return (short)(r >> 16);
}
__device__ __forceinline__ float bf2f(short b) {
  union { unsigned u; float f; } v; v.u = ((unsigned)(unsigned short)b) << 16; return v.f;
}

__device__ __forceinline__ float reduce256(float v, float* scratch) {
  for (int o = 32; o > 0; o >>= 1) v += __shfl_down(v, o, 64);
  int lane = threadIdx.x & 63, w = threadIdx.x >> 6;
  __syncthreads();
  if (lane == 0) scratch[w] = v;
  __syncthreads();
  return scratch[0] + scratch[1] + scratch[2] + scratch[3];
}

// ---------------- stats ----------------
__global__ void k_scalars(const int* y, const float* kappa, const float* nu,
                          float* kapnu, float* cf, float* beta, float* invs,
                          int* counts, int* offsets, int* cls_of_pt, int* order,
                          float* sums, float* uarr, float* dout) {
  __shared__ int h[16];
  __shared__ int cur[16];
  int t = threadIdx.x;
  if (t < 16) h[t] = 0;
  __syncthreads();
  for (int n = t; n < 4096; n += 256) atomicAdd(&h[y[n]], 1);
  __syncthreads();
  if (t == 0) {
    float kap = fabsf(kappa[0]) + 1e-6f;
    float nu_ = fmaxf(nu[0], 1024.0f - 1.0f + 1e-6f);
    kapnu[0] = kap; kapnu[1] = nu_;
    int off = 0, tile = 0;
    for (int c = 0; c < 16; c++) {
      counts[c] = h[c]; offsets[c] = off; cur[c] = off;
      cf[c] = (float)h[c];
      beta[c] = kap + (float)h[c];
      invs[c] = 1.0f / (nu_ + (float)h[c] + 1024.0f + 2.0f);
      int ntile = ((h[c] + 63) & ~63) >> 6;
      for (int q = 0; q < ntile && tile < PT_TILES; q++) cls_of_pt[tile++] = c;
      off += (h[c] + 63) & ~63;
    }
    while (tile < PT_TILES) cls_of_pt[tile++] = -1;
  }
  for (int i = t; i < NP; i += 256) order[i] = -1;
  for (int i = t; i < 16 * 1024; i += 256) { sums[i] = 0.f; uarr[i] = 0.f; }
  for (int i = t; i < 4096 * 16; i += 256) dout[i] = 0.f;
  __syncthreads();
  for (int n = t; n < 4096; n += 256) {
    int c = y[n];
    int p = atomicAdd(&cur[c], 1);
    order[p] = n;
  }
}

__global__ void k_gatherT(const float* X, const int* order, const int* cls_of_pt,
                          short* XTh, short* XTl, float* sums) {
  int pt = blockIdx.x, dt = blockIdx.y, t = threadIdx.x;
  __shared__ __align__(16) float T[64 * TS];
  __shared__ float CS[4 * 64];
  __shared__ int src[64];
  if (t < 64) src[t] = order[pt * 64 + t];
  __syncthreads();
  for (int i = 0; i < 4; i++) {
    int idx4 = i * 256 + t;
    int r = idx4 >> 4, c4 = (idx4 & 15) << 2;
    int s = src[r];
    float4 v = (s >= 0) ? *(const float4*)&X[(size_t)s * DD + dt * 64 + c4]
                        : make_float4(0.f, 0.f, 0.f, 0.f);
    *(float4*)&T[r * TS + c4] = v;
  }
  __syncthreads();
  for (int i = 0; i < 16; i++) {
    int lin = i * 256 + t;
    int d = lin >> 6, p = lin & 63;
    float v = T[p * TS + d];
    short hi = f2bf(v);
    float lov = v - bf2f(hi);
    size_t addr = (size_t)(dt * 64 + d) * NP + pt * 64 + p;
    XTh[addr] = hi;
    XTl[addr] = f2bf(lov);
  }
  int cls = cls_of_pt[pt];
  if (cls < 0) return;
  int g = t >> 6, d = t & 63;
  float s = 0.f;
  for (int p = g * 16; p < g * 16 + 16; p++) s += T[p * TS + d];
  CS[g * 64 + d] = s;
  __syncthreads();
  if (g == 0)
    atomicAdd(&sums[(size_t)cls * DD + dt * 64 + d],
              CS[d] + CS[64 + d] + CS[128 + d] + CS[192 + d]);
}

__global__ void k_mumu2(const float* sums, const float* m, const float* kapnu,
                        const float* cf, float* mu, float* mu2) {
  __shared__ float scratch[4];
  int c = blockIdx.x, t = threadIdx.x;
  float kap = kapnu[0];
  float denom = 1.0f / (kap + cf[c]);
  float s2 = 0.f;
  for (int j = t; j < DD; j += 256) {
    float v = (kap * m[j] + sums[(size_t)c * DD + j]) * denom;
    mu[(size_t)c * DD + j] = v;
    s2 += v * v;
  }
  float tot = reduce256(s2, scratch);
  if (t == 0) mu2[c] = tot;
}

__device__ __forceinline__ float lval(const float* td, const float* tl, int i, int j) {
  if (i == j) return fabsf(td[i]);
  if (i > j) return tl[(size_t)i * DD + j];
  return 0.f;
}

__global__ void k_base(const float* td, const float* tl, const float* m,
                       const float* kapnu, float* base) {
  int ti, tj; tri_decode(blockIdx.x, ti, tj);
  __shared__ float Ta[16][65], Tb[16][65];
  int t = threadIdx.x, tx = t & 15, ty = t >> 4;
  int r0 = ty * 4, c0 = tx * 4;
  float acc[4][4] = {};
  int kmax = (tj + 1) * 64;
  for (int kk = 0; kk < kmax; kk += 16) {
    __syncthreads();
    for (int idx = t; idx < 64 * 16; idx += 256) {
      int r = idx >> 4, p = idx & 15;
      Ta[p][r] = lval(td, tl, ti * 64 + r, kk + p);
      Tb[p][r] = lval(td, tl, tj * 64 + r, kk + p);
    }
    __syncthreads();
#pragma unroll
    for (int p = 0; p < 16; p++) {
      float av[4], bv[4];
#pragma unroll
      for (int a = 0; a < 4; a++) av[a] = Ta[p][r0 + a];
#pragma unroll
      for (int b = 0; b < 4; b++) bv[b] = Tb[p][c0 + b];
#pragma unroll
      for (int a = 0; a < 4; a++)
#pragma unroll
        for (int b = 0; b < 4; b++) acc[a][b] += av[a] * bv[b];
    }
  }
  float kap = kapnu[0];
#pragma unroll
  for (int a = 0; a < 4; a++)
#pragma unroll
    for (int b = 0; b < 4; b++) {
      int gi = ti * 64 + r0 + a, gj = tj * 64 + c0 + b;
      base[(size_t)gi * DD + gj] = acc[a][b] + kap * m[gi] * m[gj];
    }
}

__global__ __launch_bounds__(256) void k_syrk_mfma(const short* XTh, const short* XTl,
                                                   const float* base, const float* mu,
                                                   const float* beta, const float* invs,
                                                   const int* counts, const int* offsets,
                                                   float* sigma) {
  int bb = blockIdx.x;
  int cls = bb / 36, tr = bb % 36;
  int ti, tj; tri_decode(tr, ti, tj);
  int cnt = counts[cls], off = offsets[cls];
  float* Sg = sigma + ((size_t)cls << 20);
  const float* muc = mu + (size_t)cls * DD;
  __shared__ short Ah[128 * 40], Al[128 * 40], Bh[128 * 40], Bl[128 * 40];
  int t = threadIdx.x;
  int wave = t >> 6, lane = t & 63;
  int wr = wave >> 1, wc = wave & 1;
  int quad = lane >> 4, l15 = lane & 15;
  int i0 = ti * 128, j0 = tj * 128;
  bool same = (ti == tj);
  floatx4 acc[4][4];
#pragma unroll
  for (int a = 0; a < 4; a++)
#pragma unroll
    for (int b = 0; b < 4; b++) acc[a][b] = (floatx4){0.f, 0.f, 0.f, 0.f};
  for (int nn = 0; nn < cnt; nn += 32) {
    __syncthreads();
#pragma unroll
    for (int r = 0; r < 2; r++) {
      int lin = r * 256 + t;
      int row = lin >> 2, kg = (lin & 3) << 3;
      size_t sA = (size_t)(i0 + row) * NP + off + nn + kg;
      *(s16x8*)&Ah[row * 40 + kg] = *(const s16x8*)&XTh[sA];
      *(s16x8*)&Al[row * 40 + kg] = *(const s16x8*)&XTl[sA];
      if (!same) {
        size_t sB = (size_t)(j0 + row) * NP + off + nn + kg;
        *(s16x8*)&Bh[row * 40 + kg] = *(const s16x8*)&XTh[sB];
        *(s16x8*)&Bl[row * 40 + kg] = *(const s16x8*)&XTl[sB];
      }
    }
    __syncthreads();
    const short* PBh = same ? Ah : Bh;
    const short* PBl = same ? Al : Bl;
    s16x8 ah[4], al[4], bh[4], bl[4];
#pragma unroll
    for (int f = 0; f < 4; f++) {
      ah[f] = *(const s16x8*)&Ah[(wr * 64 + f * 16 + l15) * 40 + quad * 8];
      al[f] = *(const s16x8*)&Al[(wr * 64 + f * 16 + l15) * 40 + quad * 8];
      bh[f] = *(const s16x8*)&PBh[(wc * 64 + f * 16 + l15) * 40 + quad * 8];
      bl[f] = *(const s16x8*)&PBl[(wc * 64 + f * 16 + l15) * 40 + quad * 8];
    }
#pragma unroll
    for (int fi = 0; fi < 4; fi++)
#pragma unroll
      for (int fj = 0; fj < 4; fj++) {
        acc[fi][fj] = __builtin_amdgcn_mfma_f32_16x16x32_bf16(ah[fi], bh[fj], acc[fi][fj], 0, 0, 0);
        acc[fi][fj] = __builtin_amdgcn_mfma_f32_16x16x32_bf16(ah[fi], bl[fj], acc[fi][fj], 0, 0, 0);
        acc[fi][fj] = __builtin_amdgcn_mfma_f32_16x16x32_bf16(al[fi], bh[fj], acc[fi][fj], 0, 0, 0);
      }
  }
  float bet = beta[cls], isc = invs[cls];
#pragma unroll
  for (int fi = 0; fi < 4; fi++)
#pragma unroll
    for (int fj = 0; fj < 4; fj++)
#pragma unroll
      for (int reg = 0; reg < 4; reg++) {
        int gi = i0 + wr * 64 + fi * 16 + quad * 4 + reg;
        int gj = j0 + wc * 64 + fj * 16 + l15;
        float v = acc[fi][fj][reg] + base[(size_t)gi * DD + gj] - bet * muc[gi] * muc[gj];
        Sg[(size_t)gi * DD + gj] = v * isc;
      }
}

// ---------------- factorization ----------------
// LDL^T elimination + step-parallel inversion. Only Dinv is persisted (the
// lower R diag tile is dead downstream — R7 post-mortem).
__device__ void chol_from_lds(float* Dinv, int cls, int k, int t,
                              float* A, float* W) {
  __shared__ float sdiag[64];
  __shared__ float CSum[4 * 64];
  for (int j = 0; j < 63; j++) {
    __syncthreads();
    float rd = 1.0f / A[j * TS + j];
    for (int idx = t; idx < 4096; idx += 256) {
      int r = idx >> 6, c = idx & 63;
      if (c > j && c <= r) A[r * TS + c] -= A[r * TS + j] * A[c * TS + j] * rd;
    }
  }
  __syncthreads();
  if (t < 64) sdiag[t] = 1.0f / sqrtf(A[t * TS + t]);
  __syncthreads();
  for (int idx = t; idx < 4096; idx += 256) {
    int r = idx >> 6, c = idx & 63;
    if (r >= c) A[r * TS + c] *= sdiag[c];
    W[r * TS + c] = 0.f;
  }
  __syncthreads();
  if (t < 64) W[t * TS + t] = sdiag[t];
  __syncthreads();
  int jcol = t & 63, g = t >> 6;
  for (int i = 1; i < 64; i++) {
    float s = 0.f;
    if (jcol < i) {
      int k0 = g * 16; if (jcol > k0) k0 = jcol;
      int k1 = g * 16 + 16; if (i < k1) k1 = i;
      for (int kk = k0; kk < k1; kk++) s += A[i * TS + kk] * W[kk * TS + jcol];
    }
    CSum[g * 64 + jcol] = s;
    __syncthreads();
    if (g == 0 && jcol < i) {
      float tot = CSum[jcol] + CSum[64 + jcol] + CSum[128 + jcol] + CSum[192 + jcol];
      W[i * TS + jcol] = -sdiag[i] * tot;
    }
    __syncthreads();
  }
  float* Dv = Dinv + ((size_t)(cls * 16 + k)) * 4096;
  for (int idx4 = t; idx4 < 1024; idx4 += 256) {
    int r = idx4 >> 4, c4 = (idx4 & 15) << 2;
    *(float4*)&Dv[r * 64 + c4] = *(float4*)&W[r * TS + c4];
  }
}

__global__ void k_diag0(float* sigma, float* Dinv) {
  __shared__ __align__(16) float A[64 * TS], W[64 * TS];
  int cls = blockIdx.x, t = threadIdx.x;
  float* Sg = sigma + ((size_t)cls << 20);
  for (int idx4 = t; idx4 < 1024; idx4 += 256) {
    int r = idx4 >> 4, c4 = (idx4 & 15) << 2;
    *(float4*)&A[r * TS + c4] = *(const float4*)&Sg[(size_t)r * DD + c4];
  }
  __syncthreads();
  chol_from_lds(Dinv, cls, 0, t, A, W);
}

// merged step k: panels P_i = A(i,k)*W_k^T in LDS; b_==0 blocks persist panel
// to the UPPER mirror; trailing S(it,jt) -= P_i P_j^T (float4 RMW); special
// block factors diag k+1 in LDS.
__global__ void k_cholstep(float* sigma, float* Dinv, int k) {
  __shared__ __align__(16) float B0[64 * TS], B1[64 * TS], B2[64 * TS];
  int b = blockIdx.x, t = threadIdx.x;
  int tx = t & 15, ty = t >> 4;
  int r0 = ty * 4, c0 = tx * 4;
  int nb = 15 - k;
  int nt = nb * (nb + 1) / 2;
  int cls, a_, b_;
  bool special = (b < 16);
  if (special) { cls = b; a_ = 0; b_ = 0; }
  else {
    int jp = b - 16;
    cls = jp / (nt - 1);
    int s = jp % (nt - 1) + 1;
    tri_decode(s, a_, b_);
  }
  int it = k + 1 + a_, jt = k + 1 + b_;
  bool same = (it == jt);
  float* Sg = sigma + ((size_t)cls << 20);
  const float* Dv = Dinv + ((size_t)(cls * 16 + k)) * 4096;
  for (int i = 0; i < 4; i++) {
    int idx4 = i * 256 + t;
    int r = idx4 >> 4, c4 = (idx4 & 15) << 2;
    *(float4*)&B0[r * TS + c4] = *(const float4*)&Dv[r * 64 + c4];
    *(float4*)&B1[r * TS + c4] = *(const float4*)&Sg[(size_t)(it * 64 + r) * DD + k * 64 + c4];
    if (!same)
      *(float4*)&B2[r * TS + c4] = *(const float4*)&Sg[(size_t)(jt * 64 + r) * DD + k * 64 + c4];
  }
  __syncthreads();
  float a1[4][4] = {}, a2[4][4] = {};
#pragma unroll 8
  for (int p = 0; p < 64; p++) {
    float av[4], bv[4];
#pragma unroll
    for (int a = 0; a < 4; a++) av[a] = B1[(r0 + a) * TS + p];
#pragma unroll
    for (int bq = 0; bq < 4; bq++) bv[bq] = B0[(c0 + bq) * TS + p];
#pragma unroll
    for (int a = 0; a < 4; a++)
#pragma unroll
      for (int bq = 0; bq < 4; bq++) a1[a][bq] += av[a] * bv[bq];
  }
  if (!same) {
#pragma unroll 8
    for (int p = 0; p < 64; p++) {
      float av[4], bv[4];
#pragma unroll
      for (int a = 0; a < 4; a++) av[a] = B2[(r0 + a) * TS + p];
#pragma unroll
      for (int bq = 0; bq < 4; bq++) bv[bq] = B0[(c0 + bq) * TS + p];
#pragma unroll
      for (int a = 0; a < 4; a++)
#pragma unroll
        for (int bq = 0; bq < 4; bq++) a2[a][bq] += av[a] * bv[bq];
    }
  }
  __syncthreads();
#pragma unroll
  for (int a = 0; a < 4; a++) {
    *(float4*)&B1[(r0 + a) * TS + c0] = make_float4(a1[a][0], a1[a][1], a1[a][2], a1[a][3]);
    if (!same)
      *(float4*)&B2[(r0 + a) * TS + c0] = make_float4(a2[a][0], a2[a][1], a2[a][2], a2[a][3]);
  }
  if (b_ == 0) {
#pragma unroll
    for (int a = 0; a < 4; a++) {
      float4 v = make_float4(a1[a][0], a1[a][1], a1[a][2], a1[a][3]);
      *(float4*)&Sg[(size_t)(k * 64 + r0 + a) * DD + it * 64 + c0] = v;
    }
  }
  __syncthreads();
  float* PB = same ? B1 : B2;
  float a3[4][4] = {};
#pragma unroll 8
  for (int p = 0; p < 64; p++) {
    float av[4], bv[4];
#pragma unroll
    for (int a = 0; a < 4; a++) av[a] = B1[(r0 + a) * TS + p];
#pragma unroll
    for (int bq = 0; bq < 4; bq++) bv[bq] = PB[(c0 + bq) * TS + p];
#pragma unroll
    for (int a = 0; a < 4; a++)
#pragma unroll
      for (int bq = 0; bq < 4; bq++) a3[a][bq] += av[a] * bv[bq];
  }
  if (!special) {
#pragma unroll
    for (int a = 0; a < 4; a++) {
      size_t addr = (size_t)(it * 64 + r0 + a) * DD + jt * 64 + c0;
      float4 s = *(const float4*)&Sg[addr];
      s.x -= a3[a][0]; s.y -= a3[a][1]; s.z -= a3[a][2]; s.w -= a3[a][3];
      *(float4*)&Sg[addr] = s;
    }
    return;
  }
  __syncthreads();
#pragma unroll
  for (int a = 0; a < 4; a++) {
    size_t addr = (size_t)(it * 64 + r0 + a) * DD + jt * 64 + c0;
    float4 s = *(const float4*)&Sg[addr];
    *(float4*)&B0[(r0 + a) * TS + c0] =
        make_float4(s.x - a3[a][0], s.y - a3[a][1], s.z - a3[a][2], s.w - a3[a][3]);
  }
  __syncthreads();
  chol_from_lds(Dinv, cls, k + 1, t, B0, B2);
}

// level-1 V combine (width 64->128), fully in-LDS: V21 = -W1 * R * W0
__global__ void k_vl1(float* sigma, const float* Dinv) {
  __shared__ __align__(16) float Rl[64 * TS], W0s[64 * TS], W1s[64 * TS], Ts[64 * TS];
  int b = blockIdx.x, t = threadIdx.x;
  int cls = b >> 3, i = b & 7;
  int t0 = 2 * i, t1 = 2 * i + 1;
  float* Sg = sigma + ((size_t)cls << 20);
  int tx = t & 15, ty = t >> 4;
  int r0 = ty * 4, c0 = tx * 4;
  const float* Dv0 = Dinv + ((size_t)(cls * 16 + t0)) * 4096;
  const float* Dv1 = Dinv + ((size_t)(cls * 16 + t1)) * 4096;
  for (int idx4 = t; idx4 < 1024; idx4 += 256) {
    int r = idx4 >> 4, c4 = (idx4 & 15) << 2;
    *(float4*)&Rl[r * TS + c4] = *(const float4*)&Sg[(size_t)(t0 * 64 + r) * DD + t1 * 64 + c4];
    *(float4*)&W0s[r * TS + c4] = *(const float4*)&Dv0[r * 64 + c4];
    *(float4*)&W1s[r * TS + c4] = *(const float4*)&Dv1[r * 64 + c4];
  }
  __syncthreads();
  float aT[4][4] = {};
#pragma unroll 8
  for (int p = 0; p < 64; p++) {
    float av[4], bv[4];
#pragma unroll
    for (int a = 0; a < 4; a++) av[a] = Rl[(r0 + a) * TS + p];
#pragma unroll
    for (int bq = 0; bq < 4; bq++) bv[bq] = W0s[p * TS + c0 + bq];
#pragma unroll
    for (int a = 0; a < 4; a++)
#pragma unroll
      for (int bq = 0; bq < 4; bq++) aT[a][bq] += av[a] * bv[bq];
  }
  __syncthreads();
#pragma unroll
  for (int a = 0; a < 4; a++)
    *(float4*)&Ts[(r0 + a) * TS + c0] = make_float4(aT[a][0], aT[a][1], aT[a][2], aT[a][3]);
  __syncthreads();
  float aV[4][4] = {};
#pragma unroll 8
  for (int p = 0; p < 64; p++) {
    float av[4], bv[4];
#pragma unroll
    for (int a = 0; a < 4; a++) av[a] = W1s[(r0 + a) * TS + p];
#pragma unroll
    for (int bq = 0; bq < 4; bq++) bv[bq] = Ts[p * TS + c0 + bq];
#pragma unroll
    for (int a = 0; a < 4; a++)
#pragma unroll
      for (int bq = 0; bq < 4; bq++) aV[a][bq] += av[a] * bv[bq];
  }
#pragma unroll
  for (int a = 0; a < 4; a++)
    *(float4*)&Sg[(size_t)(t0 * 64 + r0 + a) * DD + t1 * 64 + c0] =
        make_float4(-aV[a][0], -aV[a][1], -aV[a][2], -aV[a][3]);
}

// level-L launch A: T(a,b) = sum_m R21(a,m) * V11(m,b); T -> lower scratch
__global__ void k_vlA(float* sigma, const float* Dinv, int w) {
  __shared__ __align__(16) float Xs[64 * TS], Ys[64 * TS];
  int aa = blockIdx.x / w, bb = blockIdx.x % w;
  int base = blockIdx.y * 2 * w, cls = blockIdx.z;
  float* Sg = sigma + ((size_t)cls << 20);
  int t = threadIdx.x, tx = t & 15, ty = t >> 4;
  int r0 = ty * 4, c0 = tx * 4;
  float acc[4][4] = {};
  for (int m = bb; m < w; m++) {
    __syncthreads();
    for (int idx4 = t; idx4 < 1024; idx4 += 256) {
      int r = idx4 >> 4, c4 = (idx4 & 15) << 2;
      *(float4*)&Xs[r * TS + c4] =
          *(const float4*)&Sg[(size_t)((base + m) * 64 + r) * DD + (base + w + aa) * 64 + c4];
    }
    if (m == bb) {
      const float* Dv = Dinv + ((size_t)(cls * 16 + base + bb)) * 4096;
      for (int idx4 = t; idx4 < 1024; idx4 += 256) {
        int r = idx4 >> 4, c4 = (idx4 & 15) << 2;
        *(float4*)&Ys[r * TS + c4] = *(const float4*)&Dv[r * 64 + c4];
      }
    } else {
      for (int idx4 = t; idx4 < 1024; idx4 += 256) {
        int p = idx4 >> 4, c4 = (idx4 & 15) << 2;
        *(float4*)&Ys[p * TS + c4] =
            *(const float4*)&Sg[(size_t)((base + bb) * 64 + p) * DD + (base + m) * 64 + c4];
      }
    }
    __syncthreads();
#pragma unroll 8
    for (int p = 0; p < 64; p++) {
      float av[4], bv[4];
#pragma unroll
      for (int a = 0; a < 4; a++) av[a] = Xs[(r0 + a) * TS + p];
#pragma unroll
      for (int bq = 0; bq < 4; bq++) bv[bq] = Ys[p * TS + c0 + bq];
#pragma unroll
      for (int a = 0; a < 4; a++)
#pragma unroll
        for (int bq = 0; bq < 4; bq++) acc[a][bq] += av[a] * bv[bq];
    }
  }
#pragma unroll
  for (int a = 0; a < 4; a++)
    *(float4*)&Sg[(size_t)((base + w + aa) * 64 + r0 + a) * DD + (base + bb) * 64 + c0] =
        make_float4(acc[a][0], acc[a][1], acc[a][2], acc[a][3]);
}

// level-L launch B: V21(a,b) = -sum_{m<=a} V22(a,m) * T(m,b); -> upper mirror
__global__ void k_vlB(float* sigma, const float* Dinv, int w) {
  __shared__ __align__(16) float Xs[64 * TS], Ys[64 * TS];
  int aa = blockIdx.x / w, bb = blockIdx.x % w;
  int base = blockIdx.y * 2 * w, cls = blockIdx.z;
  float* Sg = sigma + ((size_t)cls << 20);
  int t = threadIdx.x, tx = t & 15, ty = t >> 4;
  int r0 = ty * 4, c0 = tx * 4;
  float acc[4][4] = {};
  for (int m = 0; m <= aa; m++) {
    __syncthreads();
    if (m == aa) {
      const float* Dv = Dinv + ((size_t)(cls * 16 + base + w + aa)) * 4096;
      for (int idx4 = t; idx4 < 1024; idx4 += 256) {
        int r = idx4 >> 4, c4 = (idx4 & 15) << 2;
        *(float4*)&Xs[r * TS + c4] = *(const float4*)&Dv[r * 64 + c4];
      }
    } else {
      for (int idx4 = t; idx4 < 1024; idx4 += 256) {
        int r = idx4 >> 4, c4 = (idx4 & 15) << 2;
        *(float4*)&Xs[r * TS + c4] =
            *(const float4*)&Sg[(size_t)((base + w + m) * 64 + r) * DD + (base + w + aa) * 64 + c4];
      }
    }
    for (int idx4 = t; idx4 < 1024; idx4 += 256) {
      int p = idx4 >> 4, c4 = (idx4 & 15) << 2;
      *(float4*)&Ys[p * TS + c4] =
          *(const float4*)&Sg[(size_t)((base + w + m) * 64 + p) * DD + (base + bb) * 64 + c4];
    }
    __syncthreads();
#pragma unroll 8
    for (int p = 0; p < 64; p++) {
      float av[4], bv[4];
#pragma unroll
      for (int a = 0; a < 4; a++) av[a] = Xs[(r0 + a) * TS + p];
#pragma unroll
      for (int bq = 0; bq < 4; bq++) bv[bq] = Ys[p * TS + c0 + bq];
#pragma unroll
      for (int a = 0; a < 4; a++)
#pragma unroll
        for (int bq = 0; bq < 4; bq++) acc[a][bq] += av[a] * bv[bq];
    }
  }
#pragma unroll
  for (int a = 0; a < 4; a++)
    *(float4*)&Sg[(size_t)((base + bb) * 64 + r0 + a) * DD + (base + w + aa) * 64 + c0] =
        make_float4(-acc[a][0], -acc[a][1], -acc[a][2], -acc[a][3]);
}

// 2176 blocks: packed-fp16 V-tile copy (half8 writes) + fused u-partial
__global__ void k_finalize(const float* sigma, const float* Dinv, const float* mu,
                           float* uarr, _Float16* UT) {
  __shared__ __align__(16) float U0[64 * TS];
  __shared__ float CS[4 * 64];
  int jp = blockIdx.x, t = threadIdx.x;
  int cls = jp / 136, tr = jp % 136;
  int nt_, kt_; tri_decode(tr, nt_, kt_);   // nt_ >= kt_
  const float* muc = mu + (size_t)cls * DD;
  _Float16* outp = UT + (size_t)cls * UT_CLS_STRIDE + (size_t)tr * 4096;
  const float* srcp;
  size_t row_stride;
  if (kt_ == nt_) {
    srcp = Dinv + ((size_t)(cls * 16 + nt_)) * 4096;
    row_stride = 64;
  } else {
    srcp = sigma + ((size_t)cls << 20) + (size_t)(kt_ * 64) * DD + nt_ * 64;
    row_stride = DD;
  }
  for (int i = 0; i < 2; i++) {
    int g8 = i * 256 + t;            // 512 groups of 8 halves
    int rr = g8 >> 3, c8 = (g8 & 7) << 3;
    float4 v0 = *(const float4*)&srcp[(size_t)rr * row_stride + c8];
    float4 v1 = *(const float4*)&srcp[(size_t)rr * row_stride + c8 + 4];
    half8 h;
    h[0] = (_Float16)v0.x; h[1] = (_Float16)v0.y; h[2] = (_Float16)v0.z; h[3] = (_Float16)v0.w;
    h[4] = (_Float16)v1.x; h[5] = (_Float16)v1.y; h[6] = (_Float16)v1.z; h[7] = (_Float16)v1.w;
    *(half8*)&outp[rr * 64 + c8] = h;
    *(float4*)&U0[rr * TS + c8] = v0;
    *(float4*)&U0[rr * TS + c8 + 4] = v1;
  }
  __syncthreads();
  // u += V(nt_,kt_) * mu[kt_ block]; U0[r][c] = V[row r][col c]
  int g = t >> 6, r = t & 63;
  float s = 0.f;
  for (int c = g * 16; c < g * 16 + 16; c++)
    s += U0[r * TS + c] * muc[kt_ * 64 + c];
  CS[g * 64 + r] = s;
  __syncthreads();
  if (g == 0)
    atomicAdd(&uarr[(size_t)cls * DD + nt_ * 64 + r],
              CS[r] + CS[64 + r] + CS[128 + r] + CS[192 + r]);
}

// ---------------- predict side ----------------
__global__ void k_xqdots(const float* Xq, const float* mu, float* xq2, float* xqmu,
                         _Float16* XqH) {
  __shared__ float xrow[DD];
  int m = blockIdx.x, t = threadIdx.x;
  for (int i = t; i < 256; i += 256)
    ((float4*)xrow)[i] = ((const float4*)(Xq + (size_t)m * DD))[i];
  __syncthreads();
  for (int i = t; i < 256; i += 256) {
    float4 v = ((const float4*)xrow)[i];
    half4 h = {(_Float16)v.x, (_Float16)v.y, (_Float16)v.z, (_Float16)v.w};
    *(half4*)&XqH[(size_t)m * DD + i * 4] = h;
  }
  int wave = t >> 6, lane = t & 63;
  for (int cc = 0; cc < 4; cc++) {
    int c = wave * 4 + cc;
    const float* muc = mu + (size_t)c * DD;
    float s = 0.f;
    for (int j = lane; j < DD; j += 64) s += xrow[j] * muc[j];
    for (int o = 32; o > 0; o >>= 1) s += __shfl_down(s, o, 64);
    if (lane == 0) xqmu[(size_t)m * 16 + c] = s;
  }
  if (wave == 0) {
    float s = 0.f;
    for (int j = lane; j < DD; j += 64) s += xrow[j] * xrow[j];
    for (int o = 32; o > 0; o >>= 1) s += __shfl_down(s, o, 64);
    if (lane == 0) xq2[m] = s;
  }
}

__global__ __launch_bounds__(256) void k_gemmG_mfma(const _Float16* XqH, const _Float16* UT,
                                                    const float* u, float* dout) {
  int mt = blockIdx.x, ct = blockIdx.y, cls = blockIdx.z;
  const _Float16* Uc = UT + (size_t)cls * UT_CLS_STRIDE;
  __shared__ _Float16 As[128 * 40];
  __shared__ _Float16 Bs[128 * 40];
  int t = threadIdx.x;
  int wave = t >> 6, lane = t & 63;
  int wr = wave >> 1, wc = wave & 1;
  int quad = lane >> 4, l15 = lane & 15;
  int m0 = mt * 128, n0 = ct * 128, NT0 = ct * 2;
  floatx4 acc[4][4];
#pragma unroll
  for (int a = 0; a < 4; a++)
#pragma unroll
    for (int b = 0; b < 4; b++) acc[a][b] = (floatx4){0.f, 0.f, 0.f, 0.f};
  int kmax = (ct + 1) * 128;
  for (int kk = 0; kk < kmax; kk += 32) {
    __syncthreads();
#pragma unroll
    for (int i = 0; i < 2; i++) {
      int lin = i * 256 + t;
      int r = lin >> 2, kg = (lin & 3) * 8;
      *(half8*)&As[r * 40 + kg] = *(const half8*)&XqH[(size_t)(m0 + r) * DD + kk + kg];
    }
    int kt = kk >> 6, k0 = kk & 63;
#pragma unroll
    for (int i = 0; i < 2; i++) {
      int lin = i * 256 + t;
      int nl = lin >> 2, kg = (lin & 3) * 8;
      int s = nl >> 6, np = nl & 63;
      int nt = NT0 + s;
      half8 v = {};
      if (kt <= nt)
        v = *(const half8*)&Uc[(size_t)(nt * (nt + 1) / 2 + kt) * 4096 + np * 64 + k0 + kg];
      *(half8*)&Bs[nl * 40 + kg] = v;
    }
    __syncthreads();
    half8 af[4], bf[4];
#pragma unroll
    for (int f = 0; f < 4; f++) {
      af[f] = *(const half8*)&As[(wr * 64 + f * 16 + l15) * 40 + quad * 8];
      bf[f] = *(const half8*)&Bs[(wc * 64 + f * 16 + l15) * 40 + quad * 8];
    }
#pragma unroll
    for (int fi = 0; fi < 4; fi++)
#pragma unroll
      for (int fj = 0; fj < 4; fj++)
        acc[fi][fj] = __builtin_amdgcn_mfma_f32_16x16x32_f16(af[fi], bf[fj], acc[fi][fj], 0, 0, 0);
  }
  float uv[4];
#pragma unroll
  for (int fj = 0; fj < 4; fj++)
    uv[fj] = u[(size_t)cls * DD + n0 + wc * 64 + fj * 16 + l15];
#pragma unroll
  for (int fi = 0; fi < 4; fi++) {
#pragma unroll
    for (int r = 0; r < 4; r++) {
      float p = 0.f;
#pragma unroll
      for (int fj = 0; fj < 4; fj++) {
        float e = acc[fi][fj][r] - uv[fj];
        p += e * e;
      }
      p += __shfl_xor(p, 1, 64);
      p += __shfl_xor(p, 2, 64);
      p += __shfl_xor(p, 4, 64);
      p += __shfl_xor(p, 8, 64);
      if (l15 == 0) {
        int m = m0 + wr * 64 + fi * 16 + quad * 4 + r;
        atomicAdd(&dout[(size_t)m * 16 + cls], p);
      }
    }
  }
}

__global__ void k_logits(const float* xq2, const float* xqmu, const float* mu2,
                         float* dout) {
  size_t idx = (size_t)blockIdx.x * 256 + threadIdx.x;
  int m = (int)(idx >> 4), c = (int)(idx & 15);
  float q1 = dout[idx];
  float q2 = xq2[m] - 2.0f * xqmu[idx] + mu2[c];
  dout[idx] = -(0.9f * q1 + 0.1f * q2);
}

extern "C" void kernel_launch(void* const* d_in, const int* in_sizes, int n_in,
                              void* d_out, int out_size, void* d_ws, size_t ws_size,
                              hipStream_t stream) {
  (void)in_sizes; (void)n_in; (void)out_size; (void)ws_size;
  const float* X  = (const float*)d_in[0];
  const int*   y  = (const int*)d_in[1];
  const float* Xq = (const float*)d_in[2];
  const float* m  = (const float*)d_in[3];
  const float* kappa = (const float*)d_in[4];
  const float* nu = (const float*)d_in[5];
  const float* td = (const float*)d_in[6];
  const float* tl = (const float*)d_in[7];
  float* out = (float*)d_out;
  float* ws = (float*)d_ws;

  short* XTh   = (short*)(ws + OFF_XTH);
  short* XTl   = (short*)(ws + OFF_XTL);
  _Float16* UT = (_Float16*)ws;              // overlays XT planes (dead after syrk)
  float* baseb = ws + OFF_BASE;
  float* sigma = ws + OFF_SIGMA;
  _Float16* XqH = (_Float16*)sigma;          // overlays sigma (dead after finalize)
  float* Dinv  = ws + OFF_DINV;
  float* sums  = ws + OFF_SUMS;
  float* mu    = ws + OFF_MU;
  float* uarr  = ws + OFF_U;
  float* mu2   = ws + OFF_MU2;
  float* xq2   = ws + OFF_XQ2;
  float* xqmu  = ws + OFF_XQMU;
  float* kapnu = ws + OFF_KAPNU;
  float* cf    = ws + OFF_CF;
  float* beta  = ws + OFF_BETA;
  float* invs  = ws + OFF_INVS;
  int* ints      = (int*)(ws + OFF_INTS);
  int* counts    = ints;
  int* offsets   = ints + 16;
  int* cls_of_pt = ints + 32;
  int* order     = ints + 32 + PT_TILES;

  k_scalars<<<1, 256, 0, stream>>>(y, kappa, nu, kapnu, cf, beta, invs,
                                   counts, offsets, cls_of_pt, order,
                                   sums, uarr, out);
  k_gatherT<<<dim3(PT_TILES, 16), 256, 0, stream>>>(X, order, cls_of_pt, XTh, XTl, sums);
  k_mumu2<<<16, 256, 0, stream>>>(sums, m, kapnu, cf, mu, mu2);
  k_base<<<136, 256, 0, stream>>>(td, tl, m, kapnu, baseb);
  k_syrk_mfma<<<16 * 36, 256, 0, stream>>>(XTh, XTl, baseb, mu, beta, invs,
                                           counts, offsets, sigma);
  k_diag0<<<16, 256, 0, stream>>>(sigma, Dinv);
  for (int k = 0; k < 15; k++) {
    int nb = 15 - k;
    int nt = nb * (nb + 1) / 2;
    k_cholstep<<<16 * nt, 256, 0, stream>>>(sigma, Dinv, k);
  }
  k_vl1<<<128, 256, 0, stream>>>(sigma, Dinv);
  for (int L = 2; L <= 4; L++) {
    int w = 1 << (L - 1);
    int ncomb = 8 >> (L - 1);
    k_vlA<<<dim3(w * w, ncomb, 16), 256, 0, stream>>>(sigma, Dinv, w);
    k_vlB<<<dim3(w * w, ncomb, 16), 256, 0, stream>>>(sigma, Dinv, w);
  }
  k_finalize<<<16 * 136, 256, 0, stream>>>(sigma, Dinv, mu, uarr, UT);
  k_xqdots<<<4096, 256, 0, stream>>>(Xq, mu, xq2, xqmu, XqH);
  k_gemmG_mfma<<<dim3(32, 8, 16), 256, 0, stream>>>(XqH, UT, uarr, out);
  k_logits<<<256, 256, 0, stream>>>(xq2, xqmu, mu2, out);
}

// Round 9
// 2004.943 us; speedup vs baseline: 1.9252x; 1.4840x over previous
//
#include <hip/hip_runtime.h>
#include <math.h>

#define DD 1024
#define NP 5120   // padded sample pitch (class offsets padded to 64)
#define PT_TILES 80
#define TS 65     // fp32 LDS tile stride (bank-step 4 for 4-row column reads => 2-way/free)

typedef _Float16 half8 __attribute__((ext_vector_type(8)));
typedef _Float16 half4 __attribute__((ext_vector_type(4)));
typedef float floatx4 __attribute__((ext_vector_type(4)));
typedef short s16x8 __attribute__((ext_vector_type(8)));

// ---------------- workspace layout (float offsets) ----------------
#define OFF_XTH   ((size_t)0)
#define OFF_XTL   ((size_t)2621440)
#define OFF_BASE  ((size_t)5242880)
#define OFF_SIGMA ((size_t)6291456)    // 16*1024*1024 fp32 (lower: Schur, upper: R panels then V)
#define OFF_DINV  ((size_t)23068672)
#define OFF_SUMS  ((size_t)24117248)
#define OFF_MU    ((size_t)24133632)
#define OFF_U     ((size_t)24150016)
#define OFF_MU2   ((size_t)24166400)
#define OFF_XQ2   ((size_t)24166416)
#define OFF_XQMU  ((size_t)24170512)
#define OFF_KAPNU ((size_t)24236048)
#define OFF_CF    ((size_t)24236056)
#define OFF_BETA  ((size_t)24236072)
#define OFF_INVS  ((size_t)24236088)
#define OFF_INTS  ((size_t)24236104)

#define UT_CLS_STRIDE ((size_t)557056) // 136 tiles * 4096 halves

__device__ __forceinline__ void tri_decode(int b, int& ti, int& tj) {
  int t = 0;
  while ((t + 1) * (t + 2) / 2 <= b) t++;
  ti = t;
  tj = b - t * (t + 1) / 2;
}

__device__ __forceinline__ short f2bf(float f) {
  union { float f; unsigned u; } v; v.f = f;
  unsigned r = v.u + 0x7FFF + ((v.u >> 16) & 1);
  return (short)(r >> 16);
}
__device__ __forceinline__ float bf2f(short b) {
  union { unsigned u; float f; } v; v.u = ((unsigned)(unsigned short)b) << 16; return v.f;
}

__device__ __forceinline__ float reduce256(float v, float* scratch) {
  for (int o = 32; o > 0; o >>= 1) v += __shfl_down(v, o, 64);
  int lane = threadIdx.x & 63, w = threadIdx.x >> 6;
  __syncthreads();
  if (lane == 0) scratch[w] = v;
  __syncthreads();
  return scratch[0] + scratch[1] + scratch[2] + scratch[3];
}

// ---------------- stats ----------------
__global__ void k_scalars(const int* y, const float* kappa, const float* nu,
                          float* kapnu, float* cf, float* beta, float* invs,
                          int* counts, int* offsets, int* cls_of_pt, int* order,
                          float* sums, float* uarr, float* dout) {
  __shared__ int h[16];
  __shared__ int cur[16];
  int t = threadIdx.x;
  if (t < 16) h[t] = 0;
  __syncthreads();
  for (int n = t; n < 4096; n += 256) atomicAdd(&h[y[n]], 1);
  __syncthreads();
  if (t == 0) {
    float kap = fabsf(kappa[0]) + 1e-6f;
    float nu_ = fmaxf(nu[0], 1024.0f - 1.0f + 1e-6f);
    kapnu[0] = kap; kapnu[1] = nu_;
    int off = 0, tile = 0;
    for (int c = 0; c < 16; c++) {
      counts[c] = h[c]; offsets[c] = off; cur[c] = off;
      cf[c] = (float)h[c];
      beta[c] = kap + (float)h[c];
      invs[c] = 1.0f / (nu_ + (float)h[c] + 1024.0f + 2.0f);
      int ntile = ((h[c] + 63) & ~63) >> 6;
      for (int q = 0; q < ntile && tile < PT_TILES; q++) cls_of_pt[tile++] = c;
      off += (h[c] + 63) & ~63;
    }
    while (tile < PT_TILES) cls_of_pt[tile++] = -1;
  }
  for (int i = t; i < NP; i += 256) order[i] = -1;
  for (int i = t; i < 16 * 1024; i += 256) { sums[i] = 0.f; uarr[i] = 0.f; }
  for (int i = t; i < 4096 * 16; i += 256) dout[i] = 0.f;
  __syncthreads();
  for (int n = t; n < 4096; n += 256) {
    int c = y[n];
    int p = atomicAdd(&cur[c], 1);
    order[p] = n;
  }
}

__global__ void k_gatherT(const float* X, const int* order, const int* cls_of_pt,
                          short* XTh, short* XTl, float* sums) {
  int pt = blockIdx.x, dt = blockIdx.y, t = threadIdx.x;
  __shared__ float T[64 * TS];
  __shared__ float CS[4 * 64];
  __shared__ int src[64];
  if (t < 64) src[t] = order[pt * 64 + t];
  __syncthreads();
  for (int i = 0; i < 4; i++) {
    int idx4 = i * 256 + t;
    int r = idx4 >> 4, c4 = (idx4 & 15) << 2;
    int s = src[r];
    float4 v = (s >= 0) ? *(const float4*)&X[(size_t)s * DD + dt * 64 + c4]
                        : make_float4(0.f, 0.f, 0.f, 0.f);
    T[r * TS + c4] = v.x; T[r * TS + c4 + 1] = v.y;
    T[r * TS + c4 + 2] = v.z; T[r * TS + c4 + 3] = v.w;
  }
  __syncthreads();
  for (int i = 0; i < 16; i++) {
    int lin = i * 256 + t;
    int d = lin >> 6, p = lin & 63;
    float v = T[p * TS + d];
    short hi = f2bf(v);
    float lov = v - bf2f(hi);
    size_t addr = (size_t)(dt * 64 + d) * NP + pt * 64 + p;
    XTh[addr] = hi;
    XTl[addr] = f2bf(lov);
  }
  int cls = cls_of_pt[pt];
  if (cls < 0) return;
  int g = t >> 6, d = t & 63;
  float s = 0.f;
  for (int p = g * 16; p < g * 16 + 16; p++) s += T[p * TS + d];
  CS[g * 64 + d] = s;
  __syncthreads();
  if (g == 0)
    atomicAdd(&sums[(size_t)cls * DD + dt * 64 + d],
              CS[d] + CS[64 + d] + CS[128 + d] + CS[192 + d]);
}

__global__ void k_mumu2(const float* sums, const float* m, const float* kapnu,
                        const float* cf, float* mu, float* mu2) {
  __shared__ float scratch[4];
  int c = blockIdx.x, t = threadIdx.x;
  float kap = kapnu[0];
  float denom = 1.0f / (kap + cf[c]);
  float s2 = 0.f;
  for (int j = t; j < DD; j += 256) {
    float v = (kap * m[j] + sums[(size_t)c * DD + j]) * denom;
    mu[(size_t)c * DD + j] = v;
    s2 += v * v;
  }
  float tot = reduce256(s2, scratch);
  if (t == 0) mu2[c] = tot;
}

__device__ __forceinline__ float lval(const float* td, const float* tl, int i, int j) {
  if (i == j) return fabsf(td[i]);
  if (i > j) return tl[(size_t)i * DD + j];
  return 0.f;
}

__global__ void k_base(const float* td, const float* tl, const float* m,
                       const float* kapnu, float* base) {
  int ti, tj; tri_decode(blockIdx.x, ti, tj);
  __shared__ float Ta[16][65], Tb[16][65];
  int t = threadIdx.x, tx = t & 15, ty = t >> 4;
  int r0 = ty * 4, c0 = tx * 4;
  float acc[4][4] = {};
  int kmax = (tj + 1) * 64;
  for (int kk = 0; kk < kmax; kk += 16) {
    __syncthreads();
    for (int idx = t; idx < 64 * 16; idx += 256) {
      int r = idx >> 4, p = idx & 15;
      Ta[p][r] = lval(td, tl, ti * 64 + r, kk + p);
      Tb[p][r] = lval(td, tl, tj * 64 + r, kk + p);
    }
    __syncthreads();
#pragma unroll
    for (int p = 0; p < 16; p++) {
      float av[4], bv[4];
#pragma unroll
      for (int a = 0; a < 4; a++) av[a] = Ta[p][r0 + a];
#pragma unroll
      for (int b = 0; b < 4; b++) bv[b] = Tb[p][c0 + b];
#pragma unroll
      for (int a = 0; a < 4; a++)
#pragma unroll
        for (int b = 0; b < 4; b++) acc[a][b] += av[a] * bv[b];
    }
  }
  float kap = kapnu[0];
#pragma unroll
  for (int a = 0; a < 4; a++)
#pragma unroll
    for (int b = 0; b < 4; b++) {
      int gi = ti * 64 + r0 + a, gj = tj * 64 + c0 + b;
      base[(size_t)gi * DD + gj] = acc[a][b] + kap * m[gi] * m[gj];
    }
}

__global__ __launch_bounds__(256) void k_syrk_mfma(const short* XTh, const short* XTl,
                                                   const float* base, const float* mu,
                                                   const float* beta, const float* invs,
                                                   const int* counts, const int* offsets,
                                                   float* sigma) {
  int bb = blockIdx.x;
  int cls = bb / 36, tr = bb % 36;
  int ti, tj; tri_decode(tr, ti, tj);
  int cnt = counts[cls], off = offsets[cls];
  float* Sg = sigma + ((size_t)cls << 20);
  const float* muc = mu + (size_t)cls * DD;
  __shared__ short Ah[128 * 40], Al[128 * 40], Bh[128 * 40], Bl[128 * 40];
  int t = threadIdx.x;
  int wave = t >> 6, lane = t & 63;
  int wr = wave >> 1, wc = wave & 1;
  int quad = lane >> 4, l15 = lane & 15;
  int i0 = ti * 128, j0 = tj * 128;
  bool same = (ti == tj);
  floatx4 acc[4][4];
#pragma unroll
  for (int a = 0; a < 4; a++)
#pragma unroll
    for (int b = 0; b < 4; b++) acc[a][b] = (floatx4){0.f, 0.f, 0.f, 0.f};
  for (int nn = 0; nn < cnt; nn += 32) {
    __syncthreads();
#pragma unroll
    for (int r = 0; r < 2; r++) {
      int lin = r * 256 + t;
      int row = lin >> 2, kg = (lin & 3) << 3;
      size_t sA = (size_t)(i0 + row) * NP + off + nn + kg;
      *(s16x8*)&Ah[row * 40 + kg] = *(const s16x8*)&XTh[sA];
      *(s16x8*)&Al[row * 40 + kg] = *(const s16x8*)&XTl[sA];
      if (!same) {
        size_t sB = (size_t)(j0 + row) * NP + off + nn + kg;
        *(s16x8*)&Bh[row * 40 + kg] = *(const s16x8*)&XTh[sB];
        *(s16x8*)&Bl[row * 40 + kg] = *(const s16x8*)&XTl[sB];
      }
    }
    __syncthreads();
    const short* PBh = same ? Ah : Bh;
    const short* PBl = same ? Al : Bl;
    s16x8 ah[4], al[4], bh[4], bl[4];
#pragma unroll
    for (int f = 0; f < 4; f++) {
      ah[f] = *(const s16x8*)&Ah[(wr * 64 + f * 16 + l15) * 40 + quad * 8];
      al[f] = *(const s16x8*)&Al[(wr * 64 + f * 16 + l15) * 40 + quad * 8];
      bh[f] = *(const s16x8*)&PBh[(wc * 64 + f * 16 + l15) * 40 + quad * 8];
      bl[f] = *(const s16x8*)&PBl[(wc * 64 + f * 16 + l15) * 40 + quad * 8];
    }
#pragma unroll
    for (int fi = 0; fi < 4; fi++)
#pragma unroll
      for (int fj = 0; fj < 4; fj++) {
        acc[fi][fj] = __builtin_amdgcn_mfma_f32_16x16x32_bf16(ah[fi], bh[fj], acc[fi][fj], 0, 0, 0);
        acc[fi][fj] = __builtin_amdgcn_mfma_f32_16x16x32_bf16(ah[fi], bl[fj], acc[fi][fj], 0, 0, 0);
        acc[fi][fj] = __builtin_amdgcn_mfma_f32_16x16x32_bf16(al[fi], bh[fj], acc[fi][fj], 0, 0, 0);
      }
  }
  float bet = beta[cls], isc = invs[cls];
#pragma unroll
  for (int fi = 0; fi < 4; fi++)
#pragma unroll
    for (int fj = 0; fj < 4; fj++)
#pragma unroll
      for (int reg = 0; reg < 4; reg++) {
        int gi = i0 + wr * 64 + fi * 16 + quad * 4 + reg;
        int gj = j0 + wc * 64 + fj * 16 + l15;
        float v = acc[fi][fj][reg] + base[(size_t)gi * DD + gj] - bet * muc[gi] * muc[gj];
        Sg[(size_t)gi * DD + gj] = v * isc;
      }
}

// ---------------- factorization ----------------
// Register-cached LDL^T elimination (tile in regs, only column j broadcast via
// LDS, 1 barrier/step — replaces the O(64^3)-LDS-sweep version, R8 post-mortem)
// + step-parallel triangular inversion (R7-proven). Writes only Dinv.
// areg[i][b] = A[4ty+i][4tx+b]. Asc/Wsc: 64*TS LDS scratch (clobbered).
__device__ void chol_inv_reg(float areg[4][4], float* Dinv, int cls, int k, int t,
                             float* Asc, float* Wsc) {
  __shared__ float colbuf[2][64];
  __shared__ float sdiag[64];
  __shared__ float CSum[4 * 64];
  int tx = t & 15, ty = t >> 4;
  int r0 = ty * 4, c0 = tx * 4;
  for (int j = 0; j < 63; j++) {
    float* cb = colbuf[j & 1];
    if (tx == (j >> 2)) {
      int jj = j & 3;
      cb[r0 + 0] = areg[0][jj];
      cb[r0 + 1] = areg[1][jj];
      cb[r0 + 2] = areg[2][jj];
      cb[r0 + 3] = areg[3][jj];
    }
    __syncthreads();
    float rd = 1.0f / cb[j];
    float rv[4], cv[4];
#pragma unroll
    for (int i = 0; i < 4; i++) rv[i] = cb[r0 + i];
#pragma unroll
    for (int b = 0; b < 4; b++) cv[b] = cb[c0 + b];
#pragma unroll
    for (int i = 0; i < 4; i++)
#pragma unroll
      for (int b = 0; b < 4; b++)
        if (c0 + b > j && c0 + b <= r0 + i)
          areg[i][b] -= rv[i] * cv[b] * rd;
  }
  __syncthreads();
  if (tx == ty) {
#pragma unroll
    for (int i = 0; i < 4; i++) sdiag[r0 + i] = 1.0f / sqrtf(areg[i][i]);
  }
  __syncthreads();
  float sd[4];
#pragma unroll
  for (int b = 0; b < 4; b++) sd[b] = sdiag[c0 + b];
  // L (scaled, lower; 0 above) -> Asc; zero Wsc
#pragma unroll
  for (int i = 0; i < 4; i++)
#pragma unroll
    for (int b = 0; b < 4; b++) {
      float lv = (r0 + i >= c0 + b) ? areg[i][b] * sd[b] : 0.f;
      Asc[(r0 + i) * TS + c0 + b] = lv;
      Wsc[(r0 + i) * TS + c0 + b] = 0.f;
    }
  __syncthreads();
  if (t < 64) Wsc[t * TS + t] = sdiag[t];
  __syncthreads();
  // W = inv(L): row steps, 4 threads per column
  int jcol = t & 63, g = t >> 6;
  for (int i = 1; i < 64; i++) {
    float s = 0.f;
    if (jcol < i) {
      int k0 = g * 16; if (jcol > k0) k0 = jcol;
      int k1 = g * 16 + 16; if (i < k1) k1 = i;
      for (int kk = k0; kk < k1; kk++) s += Asc[i * TS + kk] * Wsc[kk * TS + jcol];
    }
    CSum[g * 64 + jcol] = s;
    __syncthreads();
    if (g == 0 && jcol < i) {
      float tot = CSum[jcol] + CSum[64 + jcol] + CSum[128 + jcol] + CSum[192 + jcol];
      Wsc[i * TS + jcol] = -sdiag[i] * tot;
    }
    __syncthreads();
  }
  float* Dv = Dinv + ((size_t)(cls * 16 + k)) * 4096;
  for (int idx4 = t; idx4 < 1024; idx4 += 256) {
    int r = idx4 >> 4, c4 = (idx4 & 15) << 2;
    float4 v = make_float4(Wsc[r * TS + c4], Wsc[r * TS + c4 + 1],
                           Wsc[r * TS + c4 + 2], Wsc[r * TS + c4 + 3]);
    *(float4*)&Dv[r * 64 + c4] = v;
  }
}

__global__ void k_diag0(float* sigma, float* Dinv) {
  __shared__ float A[64 * TS], W[64 * TS];
  int cls = blockIdx.x, t = threadIdx.x;
  int tx = t & 15, ty = t >> 4;
  int r0 = ty * 4, c0 = tx * 4;
  float* Sg = sigma + ((size_t)cls << 20);
  float areg[4][4];
#pragma unroll
  for (int i = 0; i < 4; i++) {
    float4 s = *(const float4*)&Sg[(size_t)(r0 + i) * DD + c0];
    areg[i][0] = s.x; areg[i][1] = s.y; areg[i][2] = s.z; areg[i][3] = s.w;
  }
  chol_inv_reg(areg, Dinv, cls, 0, t, A, W);
}

// merged step k: panels P_i = A(i,k)*W_k^T in LDS (mm1/mm2 share the W operand);
// b_==0 blocks persist panel to the UPPER mirror; trailing S(it,jt) -= P_i P_j^T
// (float4 RMW); special block factors diag k+1 from registers.
__global__ void k_cholstep(float* sigma, float* Dinv, int k) {
  __shared__ float B0[64 * TS], B1[64 * TS], B2[64 * TS];
  int b = blockIdx.x, t = threadIdx.x;
  int tx = t & 15, ty = t >> 4;
  int r0 = ty * 4, c0 = tx * 4;
  int nb = 15 - k;
  int nt = nb * (nb + 1) / 2;
  int cls, a_, b_;
  bool special = (b < 16);
  if (special) { cls = b; a_ = 0; b_ = 0; }
  else {
    int jp = b - 16;
    cls = jp / (nt - 1);
    int s = jp % (nt - 1) + 1;
    tri_decode(s, a_, b_);
  }
  int it = k + 1 + a_, jt = k + 1 + b_;
  bool same = (it == jt);
  float* Sg = sigma + ((size_t)cls << 20);
  const float* Dv = Dinv + ((size_t)(cls * 16 + k)) * 4096;
  for (int i = 0; i < 4; i++) {
    int idx4 = i * 256 + t;
    int r = idx4 >> 4, c4 = (idx4 & 15) << 2;
    float4 v0 = *(const float4*)&Dv[r * 64 + c4];
    B0[r * TS + c4] = v0.x; B0[r * TS + c4 + 1] = v0.y;
    B0[r * TS + c4 + 2] = v0.z; B0[r * TS + c4 + 3] = v0.w;
    float4 v1 = *(const float4*)&Sg[(size_t)(it * 64 + r) * DD + k * 64 + c4];
    B1[r * TS + c4] = v1.x; B1[r * TS + c4 + 1] = v1.y;
    B1[r * TS + c4 + 2] = v1.z; B1[r * TS + c4 + 3] = v1.w;
    if (!same) {
      float4 v2 = *(const float4*)&Sg[(size_t)(jt * 64 + r) * DD + k * 64 + c4];
      B2[r * TS + c4] = v2.x; B2[r * TS + c4 + 1] = v2.y;
      B2[r * TS + c4 + 2] = v2.z; B2[r * TS + c4 + 3] = v2.w;
    }
  }
  __syncthreads();
  // fused: a1 = B1*B0^T, a2 = B2*B0^T (shared bv)
  float a1[4][4] = {}, a2[4][4] = {};
#pragma unroll 8
  for (int p = 0; p < 64; p++) {
    float bv[4], av1[4];
#pragma unroll
    for (int bq = 0; bq < 4; bq++) bv[bq] = B0[(c0 + bq) * TS + p];
#pragma unroll
    for (int a = 0; a < 4; a++) av1[a] = B1[(r0 + a) * TS + p];
#pragma unroll
    for (int a = 0; a < 4; a++)
#pragma unroll
      for (int bq = 0; bq < 4; bq++) a1[a][bq] += av1[a] * bv[bq];
    if (!same) {
      float av2[4];
#pragma unroll
      for (int a = 0; a < 4; a++) av2[a] = B2[(r0 + a) * TS + p];
#pragma unroll
      for (int a = 0; a < 4; a++)
#pragma unroll
        for (int bq = 0; bq < 4; bq++) a2[a][bq] += av2[a] * bv[bq];
    }
  }
  __syncthreads();
#pragma unroll
  for (int a = 0; a < 4; a++)
#pragma unroll
    for (int bq = 0; bq < 4; bq++) {
      B1[(r0 + a) * TS + c0 + bq] = a1[a][bq];
      if (!same) B2[(r0 + a) * TS + c0 + bq] = a2[a][bq];
    }
  if (b_ == 0) {
#pragma unroll
    for (int a = 0; a < 4; a++) {
      float4 v = make_float4(a1[a][0], a1[a][1], a1[a][2], a1[a][3]);
      *(float4*)&Sg[(size_t)(k * 64 + r0 + a) * DD + it * 64 + c0] = v;
    }
  }
  __syncthreads();
  float* PB = same ? B1 : B2;
  float a3[4][4] = {};
#pragma unroll 8
  for (int p = 0; p < 64; p++) {
    float av[4], bv[4];
#pragma unroll
    for (int a = 0; a < 4; a++) av[a] = B1[(r0 + a) * TS + p];
#pragma unroll
    for (int bq = 0; bq < 4; bq++) bv[bq] = PB[(c0 + bq) * TS + p];
#pragma unroll
    for (int a = 0; a < 4; a++)
#pragma unroll
      for (int bq = 0; bq < 4; bq++) a3[a][bq] += av[a] * bv[bq];
  }
  if (!special) {
#pragma unroll
    for (int a = 0; a < 4; a++) {
      size_t addr = (size_t)(it * 64 + r0 + a) * DD + jt * 64 + c0;
      float4 s = *(const float4*)&Sg[addr];
      s.x -= a3[a][0]; s.y -= a3[a][1]; s.z -= a3[a][2]; s.w -= a3[a][3];
      *(float4*)&Sg[addr] = s;
    }
    return;
  }
  // special: updated (k+1,k+1) tile straight into registers, then factor
  float areg[4][4];
#pragma unroll
  for (int i = 0; i < 4; i++) {
    size_t addr = (size_t)(it * 64 + r0 + i) * DD + jt * 64 + c0;
    float4 s = *(const float4*)&Sg[addr];
    areg[i][0] = s.x - a3[i][0]; areg[i][1] = s.y - a3[i][1];
    areg[i][2] = s.z - a3[i][2]; areg[i][3] = s.w - a3[i][3];
  }
  __syncthreads();
  chol_inv_reg(areg, Dinv, cls, k + 1, t, B1, B2);
}

// level-1 V combine (width 64->128), fully in-LDS: V21 = -W1 * R * W0
__global__ void k_vl1(float* sigma, const float* Dinv) {
  __shared__ float Rl[64 * TS], W0s[64 * TS], W1s[64 * TS], Ts[64 * TS];
  int b = blockIdx.x, t = threadIdx.x;
  int cls = b >> 3, i = b & 7;
  int t0 = 2 * i, t1 = 2 * i + 1;
  float* Sg = sigma + ((size_t)cls << 20);
  int tx = t & 15, ty = t >> 4;
  int r0 = ty * 4, c0 = tx * 4;
  const float* Dv0 = Dinv + ((size_t)(cls * 16 + t0)) * 4096;
  const float* Dv1 = Dinv + ((size_t)(cls * 16 + t1)) * 4096;
  for (int idx4 = t; idx4 < 1024; idx4 += 256) {
    int r = idx4 >> 4, c4 = (idx4 & 15) << 2;
    float4 vr = *(const float4*)&Sg[(size_t)(t0 * 64 + r) * DD + t1 * 64 + c4];
    Rl[r * TS + c4] = vr.x; Rl[r * TS + c4 + 1] = vr.y;
    Rl[r * TS + c4 + 2] = vr.z; Rl[r * TS + c4 + 3] = vr.w;
    float4 v0 = *(const float4*)&Dv0[r * 64 + c4];
    W0s[r * TS + c4] = v0.x; W0s[r * TS + c4 + 1] = v0.y;
    W0s[r * TS + c4 + 2] = v0.z; W0s[r * TS + c4 + 3] = v0.w;
    float4 v1 = *(const float4*)&Dv1[r * 64 + c4];
    W1s[r * TS + c4] = v1.x; W1s[r * TS + c4 + 1] = v1.y;
    W1s[r * TS + c4 + 2] = v1.z; W1s[r * TS + c4 + 3] = v1.w;
  }
  __syncthreads();
  float aT[4][4] = {};
#pragma unroll 8
  for (int p = 0; p < 64; p++) {
    float av[4], bv[4];
#pragma unroll
    for (int a = 0; a < 4; a++) av[a] = Rl[(r0 + a) * TS + p];
#pragma unroll
    for (int bq = 0; bq < 4; bq++) bv[bq] = W0s[p * TS + c0 + bq];
#pragma unroll
    for (int a = 0; a < 4; a++)
#pragma unroll
      for (int bq = 0; bq < 4; bq++) aT[a][bq] += av[a] * bv[bq];
  }
  __syncthreads();
#pragma unroll
  for (int a = 0; a < 4; a++)
#pragma unroll
    for (int bq = 0; bq < 4; bq++) Ts[(r0 + a) * TS + c0 + bq] = aT[a][bq];
  __syncthreads();
  float aV[4][4] = {};
#pragma unroll 8
  for (int p = 0; p < 64; p++) {
    float av[4], bv[4];
#pragma unroll
    for (int a = 0; a < 4; a++) av[a] = W1s[(r0 + a) * TS + p];
#pragma unroll
    for (int bq = 0; bq < 4; bq++) bv[bq] = Ts[p * TS + c0 + bq];
#pragma unroll
    for (int a = 0; a < 4; a++)
#pragma unroll
      for (int bq = 0; bq < 4; bq++) aV[a][bq] += av[a] * bv[bq];
  }
#pragma unroll
  for (int a = 0; a < 4; a++)
    *(float4*)&Sg[(size_t)(t0 * 64 + r0 + a) * DD + t1 * 64 + c0] =
        make_float4(-aV[a][0], -aV[a][1], -aV[a][2], -aV[a][3]);
}

// level-L launch A: T(a,b) = sum_m R21(a,m) * V11(m,b); T -> lower scratch
__global__ void k_vlA(float* sigma, const float* Dinv, int w) {
  __shared__ float Xs[64 * TS], Ys[64 * TS];
  int aa = blockIdx.x / w, bb = blockIdx.x % w;
  int base = blockIdx.y * 2 * w, cls = blockIdx.z;
  float* Sg = sigma + ((size_t)cls << 20);
  int t = threadIdx.x, tx = t & 15, ty = t >> 4;
  int r0 = ty * 4, c0 = tx * 4;
  float acc[4][4] = {};
  for (int m = bb; m < w; m++) {
    __syncthreads();
    for (int idx4 = t; idx4 < 1024; idx4 += 256) {
      int r = idx4 >> 4, c4 = (idx4 & 15) << 2;
      float4 v = *(const float4*)&Sg[(size_t)((base + m) * 64 + r) * DD + (base + w + aa) * 64 + c4];
      Xs[r * TS + c4] = v.x; Xs[r * TS + c4 + 1] = v.y;
      Xs[r * TS + c4 + 2] = v.z; Xs[r * TS + c4 + 3] = v.w;
    }
    if (m == bb) {
      const float* Dv = Dinv + ((size_t)(cls * 16 + base + bb)) * 4096;
      for (int idx4 = t; idx4 < 1024; idx4 += 256) {
        int r = idx4 >> 4, c4 = (idx4 & 15) << 2;
        float4 v = *(const float4*)&Dv[r * 64 + c4];
        Ys[r * TS + c4] = v.x; Ys[r * TS + c4 + 1] = v.y;
        Ys[r * TS + c4 + 2] = v.z; Ys[r * TS + c4 + 3] = v.w;
      }
    } else {
      for (int idx4 = t; idx4 < 1024; idx4 += 256) {
        int p = idx4 >> 4, c4 = (idx4 & 15) << 2;
        float4 v = *(const float4*)&Sg[(size_t)((base + bb) * 64 + p) * DD + (base + m) * 64 + c4];
        Ys[p * TS + c4] = v.x; Ys[p * TS + c4 + 1] = v.y;
        Ys[p * TS + c4 + 2] = v.z; Ys[p * TS + c4 + 3] = v.w;
      }
    }
    __syncthreads();
#pragma unroll 8
    for (int p = 0; p < 64; p++) {
      float av[4], bv[4];
#pragma unroll
      for (int a = 0; a < 4; a++) av[a] = Xs[(r0 + a) * TS + p];
#pragma unroll
      for (int bq = 0; bq < 4; bq++) bv[bq] = Ys[p * TS + c0 + bq];
#pragma unroll
      for (int a = 0; a < 4; a++)
#pragma unroll
        for (int bq = 0; bq < 4; bq++) acc[a][bq] += av[a] * bv[bq];
    }
  }
#pragma unroll
  for (int a = 0; a < 4; a++)
    *(float4*)&Sg[(size_t)((base + w + aa) * 64 + r0 + a) * DD + (base + bb) * 64 + c0] =
        make_float4(acc[a][0], acc[a][1], acc[a][2], acc[a][3]);
}

// level-L launch B: V21(a,b) = -sum_{m<=a} V22(a,m) * T(m,b); -> upper mirror
__global__ void k_vlB(float* sigma, const float* Dinv, int w) {
  __shared__ float Xs[64 * TS], Ys[64 * TS];
  int aa = blockIdx.x / w, bb = blockIdx.x % w;
  int base = blockIdx.y * 2 * w, cls = blockIdx.z;
  float* Sg = sigma + ((size_t)cls << 20);
  int t = threadIdx.x, tx = t & 15, ty = t >> 4;
  int r0 = ty * 4, c0 = tx * 4;
  float acc[4][4] = {};
  for (int m = 0; m <= aa; m++) {
    __syncthreads();
    if (m == aa) {
      const float* Dv = Dinv + ((size_t)(cls * 16 + base + w + aa)) * 4096;
      for (int idx4 = t; idx4 < 1024; idx4 += 256) {
        int r = idx4 >> 4, c4 = (idx4 & 15) << 2;
        float4 v = *(const float4*)&Dv[r * 64 + c4];
        Xs[r * TS + c4] = v.x; Xs[r * TS + c4 + 1] = v.y;
        Xs[r * TS + c4 + 2] = v.z; Xs[r * TS + c4 + 3] = v.w;
      }
    } else {
      for (int idx4 = t; idx4 < 1024; idx4 += 256) {
        int r = idx4 >> 4, c4 = (idx4 & 15) << 2;
        float4 v = *(const float4*)&Sg[(size_t)((base + w + m) * 64 + r) * DD + (base + w + aa) * 64 + c4];
        Xs[r * TS + c4] = v.x; Xs[r * TS + c4 + 1] = v.y;
        Xs[r * TS + c4 + 2] = v.z; Xs[r * TS + c4 + 3] = v.w;
      }
    }
    for (int idx4 = t; idx4 < 1024; idx4 += 256) {
      int p = idx4 >> 4, c4 = (idx4 & 15) << 2;
      float4 v = *(const float4*)&Sg[(size_t)((base + w + m) * 64 + p) * DD + (base + bb) * 64 + c4];
      Ys[p * TS + c4] = v.x; Ys[p * TS + c4 + 1] = v.y;
      Ys[p * TS + c4 + 2] = v.z; Ys[p * TS + c4 + 3] = v.w;
    }
    __syncthreads();
#pragma unroll 8
    for (int p = 0; p < 64; p++) {
      float av[4], bv[4];
#pragma unroll
      for (int a = 0; a < 4; a++) av[a] = Xs[(r0 + a) * TS + p];
#pragma unroll
      for (int bq = 0; bq < 4; bq++) bv[bq] = Ys[p * TS + c0 + bq];
#pragma unroll
      for (int a = 0; a < 4; a++)
#pragma unroll
        for (int bq = 0; bq < 4; bq++) acc[a][bq] += av[a] * bv[bq];
    }
  }
#pragma unroll
  for (int a = 0; a < 4; a++)
    *(float4*)&Sg[(size_t)((base + bb) * 64 + r0 + a) * DD + (base + w + aa) * 64 + c0] =
        make_float4(-acc[a][0], -acc[a][1], -acc[a][2], -acc[a][3]);
}

// 2176 blocks: packed-fp16 V-tile copy (half8 writes) + fused u-partial
__global__ void k_finalize(const float* sigma, const float* Dinv, const float* mu,
                           float* uarr, _Float16* UT) {
  __shared__ float U0[64 * TS];
  __shared__ float CS[4 * 64];
  int jp = blockIdx.x, t = threadIdx.x;
  int cls = jp / 136, tr = jp % 136;
  int nt_, kt_; tri_decode(tr, nt_, kt_);   // nt_ >= kt_
  const float* muc = mu + (size_t)cls * DD;
  _Float16* outp = UT + (size_t)cls * UT_CLS_STRIDE + (size_t)tr * 4096;
  const float* srcp;
  size_t row_stride;
  if (kt_ == nt_) {
    srcp = Dinv + ((size_t)(cls * 16 + nt_)) * 4096;
    row_stride = 64;
  } else {
    srcp = sigma + ((size_t)cls << 20) + (size_t)(kt_ * 64) * DD + nt_ * 64;
    row_stride = DD;
  }
  for (int i = 0; i < 2; i++) {
    int g8 = i * 256 + t;            // 512 groups of 8 halves
    int rr = g8 >> 3, c8 = (g8 & 7) << 3;
    float4 v0 = *(const float4*)&srcp[(size_t)rr * row_stride + c8];
    float4 v1 = *(const float4*)&srcp[(size_t)rr * row_stride + c8 + 4];
    half8 h;
    h[0] = (_Float16)v0.x; h[1] = (_Float16)v0.y; h[2] = (_Float16)v0.z; h[3] = (_Float16)v0.w;
    h[4] = (_Float16)v1.x; h[5] = (_Float16)v1.y; h[6] = (_Float16)v1.z; h[7] = (_Float16)v1.w;
    *(half8*)&outp[rr * 64 + c8] = h;
    U0[rr * TS + c8] = v0.x; U0[rr * TS + c8 + 1] = v0.y;
    U0[rr * TS + c8 + 2] = v0.z; U0[rr * TS + c8 + 3] = v0.w;
    U0[rr * TS + c8 + 4] = v1.x; U0[rr * TS + c8 + 5] = v1.y;
    U0[rr * TS + c8 + 6] = v1.z; U0[rr * TS + c8 + 7] = v1.w;
  }
  __syncthreads();
  int g = t >> 6, r = t & 63;
  float s = 0.f;
  for (int c = g * 16; c < g * 16 + 16; c++)
    s += U0[r * TS + c] * muc[kt_ * 64 + c];
  CS[g * 64 + r] = s;
  __syncthreads();
  if (g == 0)
    atomicAdd(&uarr[(size_t)cls * DD + nt_ * 64 + r],
              CS[r] + CS[64 + r] + CS[128 + r] + CS[192 + r]);
}

// ---------------- predict side ----------------
__global__ void k_xqdots(const float* Xq, const float* mu, float* xq2, float* xqmu,
                         _Float16* XqH) {
  __shared__ float xrow[DD];
  int m = blockIdx.x, t = threadIdx.x;
  for (int i = t; i < 256; i += 256)
    ((float4*)xrow)[i] = ((const float4*)(Xq + (size_t)m * DD))[i];
  __syncthreads();
  for (int i = t; i < 256; i += 256) {
    float4 v = ((const float4*)xrow)[i];
    half4 h = {(_Float16)v.x, (_Float16)v.y, (_Float16)v.z, (_Float16)v.w};
    *(half4*)&XqH[(size_t)m * DD + i * 4] = h;
  }
  int wave = t >> 6, lane = t & 63;
  for (int cc = 0; cc < 4; cc++) {
    int c = wave * 4 + cc;
    const float* muc = mu + (size_t)c * DD;
    float s = 0.f;
    for (int j = lane; j < DD; j += 64) s += xrow[j] * muc[j];
    for (int o = 32; o > 0; o >>= 1) s += __shfl_down(s, o, 64);
    if (lane == 0) xqmu[(size_t)m * 16 + c] = s;
  }
  if (wave == 0) {
    float s = 0.f;
    for (int j = lane; j < DD; j += 64) s += xrow[j] * xrow[j];
    for (int o = 32; o > 0; o >>= 1) s += __shfl_down(s, o, 64);
    if (lane == 0) xq2[m] = s;
  }
}

__global__ __launch_bounds__(256) void k_gemmG_mfma(const _Float16* XqH, const _Float16* UT,
                                                    const float* u, float* dout) {
  int mt = blockIdx.x, ct = blockIdx.y, cls = blockIdx.z;
  const _Float16* Uc = UT + (size_t)cls * UT_CLS_STRIDE;
  __shared__ _Float16 As[128 * 40];
  __shared__ _Float16 Bs[128 * 40];
  int t = threadIdx.x;
  int wave = t >> 6, lane = t & 63;
  int wr = wave >> 1, wc = wave & 1;
  int quad = lane >> 4, l15 = lane & 15;
  int m0 = mt * 128, n0 = ct * 128, NT0 = ct * 2;
  floatx4 acc[4][4];
#pragma unroll
  for (int a = 0; a < 4; a++)
#pragma unroll
    for (int b = 0; b < 4; b++) acc[a][b] = (floatx4){0.f, 0.f, 0.f, 0.f};
  int kmax = (ct + 1) * 128;
  for (int kk = 0; kk < kmax; kk += 32) {
    __syncthreads();
#pragma unroll
    for (int i = 0; i < 2; i++) {
      int lin = i * 256 + t;
      int r = lin >> 2, kg = (lin & 3) * 8;
      *(half8*)&As[r * 40 + kg] = *(const half8*)&XqH[(size_t)(m0 + r) * DD + kk + kg];
    }
    int kt = kk >> 6, k0 = kk & 63;
#pragma unroll
    for (int i = 0; i < 2; i++) {
      int lin = i * 256 + t;
      int nl = lin >> 2, kg = (lin & 3) * 8;
      int s = nl >> 6, np = nl & 63;
      int nt = NT0 + s;
      half8 v = {};
      if (kt <= nt)
        v = *(const half8*)&Uc[(size_t)(nt * (nt + 1) / 2 + kt) * 4096 + np * 64 + k0 + kg];
      *(half8*)&Bs[nl * 40 + kg] = v;
    }
    __syncthreads();
    half8 af[4], bf[4];
#pragma unroll
    for (int f = 0; f < 4; f++) {
      af[f] = *(const half8*)&As[(wr * 64 + f * 16 + l15) * 40 + quad * 8];
      bf[f] = *(const half8*)&Bs[(wc * 64 + f * 16 + l15) * 40 + quad * 8];
    }
#pragma unroll
    for (int fi = 0; fi < 4; fi++)
#pragma unroll
      for (int fj = 0; fj < 4; fj++)
        acc[fi][fj] = __builtin_amdgcn_mfma_f32_16x16x32_f16(af[fi], bf[fj], acc[fi][fj], 0, 0, 0);
  }
  float uv[4];
#pragma unroll
  for (int fj = 0; fj < 4; fj++)
    uv[fj] = u[(size_t)cls * DD + n0 + wc * 64 + fj * 16 + l15];
#pragma unroll
  for (int fi = 0; fi < 4; fi++) {
#pragma unroll
    for (int r = 0; r < 4; r++) {
      float p = 0.f;
#pragma unroll
      for (int fj = 0; fj < 4; fj++) {
        float e = acc[fi][fj][r] - uv[fj];
        p += e * e;
      }
      p += __shfl_xor(p, 1, 64);
      p += __shfl_xor(p, 2, 64);
      p += __shfl_xor(p, 4, 64);
      p += __shfl_xor(p, 8, 64);
      if (l15 == 0) {
        int m = m0 + wr * 64 + fi * 16 + quad * 4 + r;
        atomicAdd(&dout[(size_t)m * 16 + cls], p);
      }
    }
  }
}

__global__ void k_logits(const float* xq2, const float* xqmu, const float* mu2,
                         float* dout) {
  size_t idx = (size_t)blockIdx.x * 256 + threadIdx.x;
  int m = (int)(idx >> 4), c = (int)(idx & 15);
  float q1 = dout[idx];
  float q2 = xq2[m] - 2.0f * xqmu[idx] + mu2[c];
  dout[idx] = -(0.9f * q1 + 0.1f * q2);
}

extern "C" void kernel_launch(void* const* d_in, const int* in_sizes, int n_in,
                              void* d_out, int out_size, void* d_ws, size_t ws_size,
                              hipStream_t stream) {
  (void)in_sizes; (void)n_in; (void)out_size; (void)ws_size;
  const float* X  = (const float*)d_in[0];
  const int*   y  = (const int*)d_in[1];
  const float* Xq = (const float*)d_in[2];
  const float* m  = (const float*)d_in[3];
  const float* kappa = (const float*)d_in[4];
  const float* nu = (const float*)d_in[5];
  const float* td = (const float*)d_in[6];
  const float* tl = (const float*)d_in[7];
  float* out = (float*)d_out;
  float* ws = (float*)d_ws;

  short* XTh   = (short*)(ws + OFF_XTH);
  short* XTl   = (short*)(ws + OFF_XTL);
  _Float16* UT = (_Float16*)ws;              // overlays XT planes (dead after syrk)
  float* baseb = ws + OFF_BASE;
  float* sigma = ws + OFF_SIGMA;
  _Float16* XqH = (_Float16*)sigma;          // overlays sigma (dead after finalize)
  float* Dinv  = ws + OFF_DINV;
  float* sums  = ws + OFF_SUMS;
  float* mu    = ws + OFF_MU;
  float* uarr  = ws + OFF_U;
  float* mu2   = ws + OFF_MU2;
  float* xq2   = ws + OFF_XQ2;
  float* xqmu  = ws + OFF_XQMU;
  float* kapnu = ws + OFF_KAPNU;
  float* cf    = ws + OFF_CF;
  float* beta  = ws + OFF_BETA;
  float* invs  = ws + OFF_INVS;
  int* ints      = (int*)(ws + OFF_INTS);
  int* counts    = ints;
  int* offsets   = ints + 16;
  int* cls_of_pt = ints + 32;
  int* order     = ints + 32 + PT_TILES;

  k_scalars<<<1, 256, 0, stream>>>(y, kappa, nu, kapnu, cf, beta, invs,
                                   counts, offsets, cls_of_pt, order,
                                   sums, uarr, out);
  k_gatherT<<<dim3(PT_TILES, 16), 256, 0, stream>>>(X, order, cls_of_pt, XTh, XTl, sums);
  k_mumu2<<<16, 256, 0, stream>>>(sums, m, kapnu, cf, mu, mu2);
  k_base<<<136, 256, 0, stream>>>(td, tl, m, kapnu, baseb);
  k_syrk_mfma<<<16 * 36, 256, 0, stream>>>(XTh, XTl, baseb, mu, beta, invs,
                                           counts, offsets, sigma);
  k_diag0<<<16, 256, 0, stream>>>(sigma, Dinv);
  for (int k = 0; k < 15; k++) {
    int nb = 15 - k;
    int nt = nb * (nb + 1) / 2;
    k_cholstep<<<16 * nt, 256, 0, stream>>>(sigma, Dinv, k);
  }
  k_vl1<<<128, 256, 0, stream>>>(sigma, Dinv);
  for (int L = 2; L <= 4; L++) {
    int w = 1 << (L - 1);
    int ncomb = 8 >> (L - 1);
    k_vlA<<<dim3(w * w, ncomb, 16), 256, 0, stream>>>(sigma, Dinv, w);
    k_vlB<<<dim3(w * w, ncomb, 16), 256, 0, stream>>>(sigma, Dinv, w);
  }
  k_finalize<<<16 * 136, 256, 0, stream>>>(sigma, Dinv, mu, uarr, UT);
  k_xqdots<<<4096, 256, 0, stream>>>(Xq, mu, xq2, xqmu, XqH);
  k_gemmG_mfma<<<dim3(32, 8, 16), 256, 0, stream>>>(XqH, UT, uarr, out);
  k_logits<<<256, 256, 0, stream>>>(xq2, xqmu, mu2, out);
}